// Round 4
// baseline (418.088 us; speedup 1.0000x reference)
//
#include <hip/hip_runtime.h>
#include <hip/hip_bf16.h>
#include <math.h>

#define NR 4096
#define UD 64
#define BD 256
#define SD 256
#define RD 512
#define UBD 16384
#define DECAY 0.99f

typedef unsigned short ushort_t;
typedef _Float16 f16x8 __attribute__((ext_vector_type(8)));
typedef __attribute__((ext_vector_type(4))) float f32x4;

// output offsets (in floats), concatenated in reference return order
#define OFF_MDR   0ull          // memory_delta_rule   [4096,512]
#define OFF_MSIG  2097152ull    // memory_signature    [4096,256]
#define OFF_MCONF 3145728ull    // memory_conf         [4096,1]
#define OFF_NDP   3149824ull    // new_delta_proto     [64,256,512]
#define OFF_NSP   11538432ull   // new_signature_proto [64,256,256]
#define OFF_NEC   15732736ull   // new_ema_conf        [64,256]
#define OFF_NUS   15749120ull   // new_usage           [64,256]
#define OFF_SCAL  15765504ull   // write_rate, usage_fraction, usage_entropy

static __device__ __forceinline__ ushort_t f2h(float x) {
  _Float16 h = (_Float16)x;    // RNE
  ushort_t u;
  __builtin_memcpy(&u, &h, 2);
  return u;
}

static __device__ __forceinline__ void gll16(const void* g, void* l) {
  __builtin_amdgcn_global_load_lds(
      (const __attribute__((address_space(1))) unsigned int*)g,
      (__attribute__((address_space(3))) unsigned int*)l, 16, 0, 0);
}

// ---------------------------------------------------------------------------
// Detect how write_mask (jax bool) was delivered: int32 (2), float32 (1), byte (0)
__global__ void detect_mask_kernel(const unsigned char* __restrict__ wm,
                                   int* __restrict__ flag)
{
  if (threadIdx.x != 0 || blockIdx.x != 0) return;
  const int*   wi = (const int*)wm;
  const float* wf = (const float*)wm;
  bool is_i32 = true, is_f32 = true;
  for (int i = 0; i < 16; ++i) {
    int v = wi[i];
    if (v != 0 && v != 1) is_i32 = false;
    float f = wf[i];
    if (f != 0.f && f != 1.f) is_f32 = false;
  }
  *flag = is_i32 ? 2 : (is_f32 ? 1 : 0);
}

// ---------------------------------------------------------------------------
// Per-row: denom, unnormalized base_conf, argmax(q_u), argmax(q_b), wgt, cell, m
__global__ __launch_bounds__(256) void row_prep_kernel(
    const float* __restrict__ q_u, const float* __restrict__ q_b,
    const float* __restrict__ usage, const float* __restrict__ ema,
    const unsigned char* __restrict__ wm, const int* __restrict__ flag,
    float* __restrict__ denom, float* __restrict__ base_raw,
    float* __restrict__ wgt, int* __restrict__ cellid, float* __restrict__ mrow)
{
  const int n = blockIdx.x;
  const int t = threadIdx.x;
  __shared__ float s_qu[UD];
  __shared__ float r1[256];
  __shared__ float r2[256];
  __shared__ int   ri[256];
  if (t < UD) s_qu[t] = q_u[(size_t)n * UD + t];
  __syncthreads();
  const float qb = q_b[(size_t)n * BD + t];
  float accd = 0.f, accc = 0.f;
  #pragma unroll 4
  for (int u = 0; u < UD; ++u) {
    const int idx = u * BD + t;
    if (usage[idx] > 0.f) {
      const float qu = s_qu[u];
      accd += qu;
      accc += qu * ema[idx];
    }
  }
  accd *= qb; accc *= qb;
  r1[t] = accd; r2[t] = accc;
  __syncthreads();
  for (int s = 128; s > 0; s >>= 1) {
    if (t < s) { r1[t] += r1[t + s]; r2[t] += r2[t + s]; }
    __syncthreads();
  }
  const float dsum = r1[0];
  const float csum = r2[0];
  __syncthreads();
  // argmax over q_b (first-index tie-break)
  r1[t] = qb; ri[t] = t;
  __syncthreads();
  for (int s = 128; s > 0; s >>= 1) {
    if (t < s) {
      float v2 = r1[t + s]; int i2 = ri[t + s];
      if (v2 > r1[t] || (v2 == r1[t] && i2 < ri[t])) { r1[t] = v2; ri[t] = i2; }
    }
    __syncthreads();
  }
  const float bmax = r1[0]; const int bidx = ri[0];
  __syncthreads();
  // argmax over q_u
  r1[t] = (t < UD) ? s_qu[t] : -1e30f; ri[t] = t;
  __syncthreads();
  for (int s = 128; s > 0; s >>= 1) {
    if (t < s) {
      float v2 = r1[t + s]; int i2 = ri[t + s];
      if (v2 > r1[t] || (v2 == r1[t] && i2 < ri[t])) { r1[t] = v2; ri[t] = i2; }
    }
    __syncthreads();
  }
  if (t == 0) {
    const float umax = r1[0]; const int uidx = ri[0];
    const int fm = *flag;
    float m;
    if (fm == 2)      m = (((const int*)wm)[n]   != 0)   ? 1.f : 0.f;
    else if (fm == 1) m = (((const float*)wm)[n] != 0.f) ? 1.f : 0.f;
    else              m = (wm[n] != 0) ? 1.f : 0.f;
    denom[n]    = dsum;
    base_raw[n] = csum;
    wgt[n]      = umax * bmax * m;
    cellid[n]   = uidx * BD + bidx;
    mrow[n]     = m;
  }
}

// ---------------------------------------------------------------------------
// q_b -> fp16 (for register A-fragment generation in the GEMM)
__global__ __launch_bounds__(256) void qb_half_kernel(
    const float* __restrict__ qb, ushort_t* __restrict__ qb16)
{
  const int i = blockIdx.x * 256 + threadIdx.x;   // 262144 threads, 4 elems each
  const float4 v = *(const float4*)(qb + (size_t)i * 4);
  ushort_t tmp[4] = { f2h(v.x), f2h(v.y), f2h(v.z), f2h(v.w) };
  uint2 w; __builtin_memcpy(&w, tmp, 8);
  *(uint2*)(qb16 + (size_t)i * 4) = w;
}

// ---------------------------------------------------------------------------
// Precompute masked, TRANSPOSED fp16 proto: PT[c][k], c in [0,768), k in [0,16384)
__global__ __launch_bounds__(256) void transpose_mask_kernel(
    const float* __restrict__ dproto, const float* __restrict__ sproto,
    const float* __restrict__ usage, ushort_t* __restrict__ PT)
{
  __shared__ ushort_t s[64][66];
  const int k0 = blockIdx.x * 64;
  const int rblk = blockIdx.y;       // 0..11
  const float* src; int ld; int c0s;
  if (rblk < 8) { src = dproto; ld = RD; c0s = rblk * 64; }
  else          { src = sproto; ld = SD; c0s = (rblk - 8) * 64; }
  const int tid = threadIdx.x;
  const int kl = tid >> 4;           // 0..15
  const int rl = (tid & 15) * 4;
  #pragma unroll
  for (int i = 0; i < 4; ++i) {
    const int k = kl + i * 16;
    const bool valid = usage[k0 + k] > 0.f;
    const float4 v = *(const float4*)(src + (size_t)(k0 + k) * ld + c0s + rl);
    s[k][rl + 0] = valid ? f2h(v.x) : (ushort_t)0;
    s[k][rl + 1] = valid ? f2h(v.y) : (ushort_t)0;
    s[k][rl + 2] = valid ? f2h(v.z) : (ushort_t)0;
    s[k][rl + 3] = valid ? f2h(v.w) : (ushort_t)0;
  }
  __syncthreads();
  const int rl2 = tid >> 4;
  const int kl2 = (tid & 15) * 4;
  #pragma unroll
  for (int i = 0; i < 4; ++i) {
    const int r = rl2 + i * 16;
    ushort_t tmp[4] = { s[kl2 + 0][r], s[kl2 + 1][r], s[kl2 + 2][r], s[kl2 + 3][r] };
    uint2 w; __builtin_memcpy(&w, tmp, 8);
    *(uint2*)(PT + (size_t)(rblk * 64 + r) * UBD + k0 + kl2) = w;
  }
}

// ---------------------------------------------------------------------------
// MFMA retrieve GEMM (fp16): Craw[n,c] += sum_k (qu[n]*qb16[n,k&255]) * PT[c,k]
// 128x128 tile, BK=64, 4 waves (2x2), split-K x4, atomicAdd epilogue.
// A-fragments in registers; B via global_load_lds w/ pre-swizzled source.
// Grid is FLAT 768 blocks with XCD-aware decode: each XCD owns 3 (y,z)
// combos x 32 n-tiles, so the 1MB PT slice per combo is L2-resident (T1).
#define GBK 64

__global__ __launch_bounds__(256, 3) void mfma_gemm_kernel(
    const float* __restrict__ q_u, const ushort_t* __restrict__ qb16,
    const ushort_t* __restrict__ PT, float* __restrict__ out)
{
  __shared__ ushort_t sB[2][128 * 64];   // [buf][col][k] fp16, swizzle via source
  const int tid = threadIdx.x;
  const int wid = tid >> 6, lane = tid & 63;

  // ---- XCD-aware block decode: lin%8 = XCD (round-robin dispatch)
  const int lin  = blockIdx.x;          // 0..767
  const int xcd  = lin & 7;
  const int slot = lin >> 3;            // 0..95
  const int combo = xcd * 3 + (slot >> 5);  // 0..23, 3 combos per XCD
  const int bx = slot & 31;             // n-tile 0..31
  const int by = combo >> 2;            // col-tile 0..5
  const int bz = combo & 3;             // k-split 0..3

  const int n0 = bx * 128;
  const int kbeg = bz * (UBD / 4);
  const int kend = kbeg + UBD / 4;

  float* obase; int ldO; int cc0;
  if (by < 4) { obase = out + OFF_MDR;  ldO = RD; cc0 = by * 128; }
  else        { obase = out + OFF_MSIG; ldO = SD; cc0 = (by - 4) * 128; }
  const int c0 = by * 128;    // global PT row (col index 0..767)

  // ---- staging geometry: wave w stages sB rows [w*32, w*32+32), 4 gll x 1KB
  const int srowbase = wid * 32;
  const int chunk_src = (lane & 7) ^ (lane >> 3);
  const ushort_t* gsrc0 = PT + (size_t)(c0 + srowbase + (lane >> 3)) * UBD
                             + kbeg + chunk_src * 8;

  // ---- fragment geometry
  const int wr = (wid >> 1) * 64, wc = (wid & 1) * 64;
  const int fr  = lane & 15;
  const int fke = (lane >> 4) * 8;       // A frag element offset in k
  const int fkb = (lane >> 4) * 16;      // B frag byte offset within 128B row

  uint addrB[4][2];
  #pragma unroll
  for (int nn = 0; nn < 4; ++nn)
    #pragma unroll
    for (int ks = 0; ks < 2; ++ks)
      addrB[nn][ks] = (uint)((((wc + nn * 16 + fr) * 128) + ks * 64 + fkb)
                             ^ ((fr & 7) << 4));

  const ushort_t* qbrow[4];
  const float* qurow[4];
  #pragma unroll
  for (int m = 0; m < 4; ++m) {
    const int row = n0 + wr + m * 16 + fr;
    qbrow[m] = qb16 + (size_t)row * BD;
    qurow[m] = q_u + (size_t)row * UD;
  }

  f32x4 acc[4][4];
  #pragma unroll
  for (int m = 0; m < 4; ++m)
    #pragma unroll
    for (int nn = 0; nn < 4; ++nn)
      acc[m][nn] = (f32x4){0.f, 0.f, 0.f, 0.f};

  // ---- prologue: stage buf0
  #pragma unroll
  for (int i = 0; i < 4; ++i)
    gll16(gsrc0 + (size_t)i * 8 * UBD, &sB[0][(srowbase + i * 8) * 64]);
  __syncthreads();

  // ---- main loop: outer over u (4 per split), inner 4 k-steps of 64
  for (int k0 = kbeg; k0 < kend; k0 += 256) {
    const int u = k0 >> 8;
    f16x8 qs[4];
    #pragma unroll
    for (int m = 0; m < 4; ++m) {
      const _Float16 h = (_Float16)qurow[m][u];
      #pragma unroll
      for (int j = 0; j < 8; ++j) qs[m][j] = h;
    }
    #pragma unroll
    for (int bq = 0; bq < 4; ++bq) {
      const int kk = k0 + bq * GBK;
      const int cur = ((kk - kbeg) >> 6) & 1;
      const int b0 = bq * 64;
      // A fragment loads (16B each, L1/L2-served)
      f16x8 aa[4][2];
      #pragma unroll
      for (int m = 0; m < 4; ++m)
        #pragma unroll
        for (int ks = 0; ks < 2; ++ks)
          aa[m][ks] = *(const f16x8*)(qbrow[m] + b0 + ks * 32 + fke);
      // issue next-tile B stage (async; drained by the syncthreads below)
      const int kn = kk + GBK;
      if (kn < kend) {
        const ushort_t* gs = gsrc0 + (kn - kbeg);
        #pragma unroll
        for (int i = 0; i < 4; ++i)
          gll16(gs + (size_t)i * 8 * UBD, &sB[cur ^ 1][(srowbase + i * 8) * 64]);
      }
      // A frags: packed fp16 multiply
      f16x8 av[4][2];
      #pragma unroll
      for (int m = 0; m < 4; ++m)
        #pragma unroll
        for (int ks = 0; ks < 2; ++ks)
          av[m][ks] = aa[m][ks] * qs[m];
      // B frags from LDS + MFMA
      const char* sb = (const char*)&sB[cur][0];
      #pragma unroll
      for (int ks = 0; ks < 2; ++ks) {
        f16x8 bv[4];
        #pragma unroll
        for (int nn = 0; nn < 4; ++nn)
          bv[nn] = *(const f16x8*)(sb + addrB[nn][ks]);
        #pragma unroll
        for (int m = 0; m < 4; ++m)
          #pragma unroll
          for (int nn = 0; nn < 4; ++nn)
            acc[m][nn] = __builtin_amdgcn_mfma_f32_16x16x32_f16(av[m][ks], bv[nn],
                                                                acc[m][nn], 0, 0, 0);
      }
      __syncthreads();
    }
  }
  // ---- epilogue: atomic accumulate raw sums (scaled later by 1/denom)
  const int orow = (lane >> 4) * 4;
  #pragma unroll
  for (int m = 0; m < 4; ++m) {
    #pragma unroll
    for (int nn = 0; nn < 4; ++nn) {
      const int c = cc0 + wc + nn * 16 + fr;
      #pragma unroll
      for (int j = 0; j < 4; ++j) {
        const int r = n0 + wr + m * 16 + orow + j;
        atomicAdd(obase + (size_t)r * ldO + c, acc[m][nn][j]);
      }
    }
  }
}

// ---------------------------------------------------------------------------
// Scale raw GEMM sums by 1/denom in place; fuse memory_conf (cosine) computation
__global__ __launch_bounds__(256) void epilogue_kernel(
    const float* __restrict__ q_sigma, const float* __restrict__ denom,
    const float* __restrict__ base_raw, float* __restrict__ out)
{
  const int n = blockIdx.x;
  const int t = threadIdx.x;
  __shared__ float r1[256], r2[256], r3[256];
  const float d = denom[n];
  const float scale = (d > 0.f) ? (1.f / fmaxf(d, 1e-6f)) : 0.f;
  float* mdr = out + OFF_MDR + (size_t)n * RD;
  mdr[t]       *= scale;
  mdr[t + 256] *= scale;
  float* msig = out + OFF_MSIG + (size_t)n * SD;
  const float s = msig[t] * scale;
  msig[t] = s;
  const float a = q_sigma[(size_t)n * SD + t];
  const float b = s + 1e-6f;
  r1[t] = a * a; r2[t] = b * b; r3[t] = a * b;
  __syncthreads();
  for (int st = 128; st > 0; st >>= 1) {
    if (t < st) { r1[t] += r1[t + st]; r2[t] += r2[t + st]; r3[t] += r3[t + st]; }
    __syncthreads();
  }
  if (t == 0) {
    const float na = fmaxf(sqrtf(r1[0]), 1e-12f);
    const float nb = fmaxf(sqrtf(r2[0]), 1e-12f);
    const float cosv = r3[0] / (na * nb);
    const float agree = 0.5f * (1.f + cosv);
    const float base = (d > 0.f) ? base_raw[n] / fmaxf(d, 1e-6f) : 0.f;
    out[OFF_MCONF + n] = fminf(fmaxf(base * agree, 0.f), 1.f);
  }
}

// ---------------------------------------------------------------------------
// Scatter segment-sums into the (zeroed) new_*_proto output regions + sum_w/cnt
__global__ __launch_bounds__(256) void scatter_kernel(
    const float* __restrict__ dtarget, const float* __restrict__ q_sigma,
    const float* __restrict__ wgt, const int* __restrict__ cellid,
    const float* __restrict__ mrow,
    float* __restrict__ sumd, float* __restrict__ sums,
    float* __restrict__ sum_w, float* __restrict__ cnt)
{
  const int n = blockIdx.x;
  if (mrow[n] == 0.f) return;
  const int t = threadIdx.x;
  const int c = cellid[n];
  const float w = wgt[n];
  atomicAdd(&sumd[(size_t)c * RD + t],       dtarget[(size_t)n * RD + t] * w);
  atomicAdd(&sumd[(size_t)c * RD + t + 256], dtarget[(size_t)n * RD + t + 256] * w);
  atomicAdd(&sums[(size_t)c * SD + t],       q_sigma[(size_t)n * SD + t] * w);
  if (t == 0) { atomicAdd(&sum_w[c], w); atomicAdd(&cnt[c], 1.f); }
}

// ---------------------------------------------------------------------------
// In-place EMA transform of proto sums -> new protos
__global__ __launch_bounds__(256) void ema_proto_kernel(
    const float* __restrict__ dproto, const float* __restrict__ sproto,
    const float* __restrict__ sum_w, const float* __restrict__ cnt,
    float* __restrict__ outd, float* __restrict__ outs)
{
  const size_t nd = (size_t)UBD * RD;          // 8388608
  const size_t total = nd + (size_t)UBD * SD;  // 12582912
  for (size_t i = (size_t)blockIdx.x * 256 + threadIdx.x; i < total;
       i += (size_t)gridDim.x * 256) {
    if (i < nd) {
      const int cell = (int)(i >> 9);
      const float c = cnt[cell];
      float v;
      if (c > 0.f) {
        const float cs = fmaxf(sum_w[cell], 1e-6f);
        v = DECAY * dproto[i] + (1.f - DECAY) * (outd[i] / cs);
      } else v = dproto[i];
      outd[i] = v;
    } else {
      const size_t j = i - nd;
      const int cell = (int)(j >> 8);
      const float c = cnt[cell];
      float v;
      if (c > 0.f) {
        const float cs = fmaxf(sum_w[cell], 1e-6f);
        v = DECAY * sproto[j] + (1.f - DECAY) * (outs[j] / cs);
      } else v = sproto[j];
      outs[j] = v;
    }
  }
}

// ---------------------------------------------------------------------------
__global__ __launch_bounds__(256) void ema_small_kernel(
    const float* __restrict__ ema, const float* __restrict__ usage,
    const float* __restrict__ sum_w, const float* __restrict__ cnt,
    float* __restrict__ out_ec, float* __restrict__ out_us)
{
  const int i = blockIdx.x * 256 + threadIdx.x;
  if (i < UBD) {
    const float c = cnt[i];
    const float cm = sum_w[i] / fmaxf(c, 1.f);
    out_ec[i] = (c > 0.f) ? DECAY * ema[i] + (1.f - DECAY) * cm : ema[i];
    out_us[i] = usage[i] + c;
  }
}

// ---------------------------------------------------------------------------
// write_rate, usage_fraction, usage_entropy (single block)
__global__ __launch_bounds__(256) void stats_kernel(
    const float* __restrict__ cnt, const float* __restrict__ new_us,
    float* __restrict__ out_scalars)
{
  const int t = threadIdx.x;
  __shared__ float r1[256], r2[256], r3[256];
  float scnt = 0.f, snz = 0.f, sus = 0.f;
  for (int i = t; i < UBD; i += 256) {
    const float c = cnt[i]; scnt += c;
    const float u = new_us[i];
    if (u > 0.f) snz += 1.f;
    sus += u;
  }
  r1[t] = scnt; r2[t] = snz; r3[t] = sus;
  __syncthreads();
  for (int s = 128; s > 0; s >>= 1) {
    if (t < s) { r1[t] += r1[t + s]; r2[t] += r2[t + s]; r3[t] += r3[t + s]; }
    __syncthreads();
  }
  const float total_cnt = r1[0], total_nz = r2[0], total_us = r3[0];
  __syncthreads();
  const float S = fmaxf(total_us, 1e-6f);
  float ent = 0.f;
  for (int i = t; i < UBD; i += 256) {
    const float d = new_us[i] / S;
    ent += d * logf(d + 1e-6f);
  }
  r1[t] = ent;
  __syncthreads();
  for (int s = 128; s > 0; s >>= 1) {
    if (t < s) { r1[t] += r1[t + s]; }
    __syncthreads();
  }
  if (t == 0) {
    out_scalars[0] = total_cnt / (float)NR;
    out_scalars[1] = total_nz / (float)UBD;
    out_scalars[2] = -r1[0] / 9.70406053f;   // ln(16384)
  }
}

// ---------------------------------------------------------------------------
extern "C" void kernel_launch(void* const* d_in, const int* in_sizes, int n_in,
                              void* d_out, int out_size, void* d_ws, size_t ws_size,
                              hipStream_t stream)
{
  const float* q_u    = (const float*)d_in[0];
  const float* q_b    = (const float*)d_in[1];
  const float* q_sig  = (const float*)d_in[2];
  const float* dtg    = (const float*)d_in[3];
  const unsigned char* wm = (const unsigned char*)d_in[4];
  const float* dproto = (const float*)d_in[5];
  const float* sproto = (const float*)d_in[6];
  const float* ema    = (const float*)d_in[7];
  const float* usage  = (const float*)d_in[8];
  float* out = (float*)d_out;

  float* wsf = (float*)d_ws;
  int*   wsi = (int*)d_ws;
  int*   flag     = wsi;                       // [16]
  float* denom    = wsf + 16;                  // [4096]
  float* base_raw = wsf + 16 + 4096;           // [4096]
  float* wgtb     = wsf + 16 + 8192;           // [4096]
  int*   cellid   = wsi + 16 + 12288;          // [4096]
  float* mrow     = wsf + 16 + 16384;          // [4096]
  float* sum_w    = wsf + 16 + 20480;          // [16384]
  float* cnt      = wsf + 16 + 20480 + 16384;  // [16384]

  // PT (fp16 masked transposed proto, 768x16384 = 25.2 MB) and qb16 (2 MB)
  // park in the NDP output region, which is rewritten only after the GEMM.
  ushort_t* PT   = (ushort_t*)(out + OFF_NDP);
  ushort_t* qb16 = PT + (size_t)768 * UBD;

  qb_half_kernel<<<(NR * BD / 4) / 256, 256, 0, stream>>>(q_b, qb16);
  transpose_mask_kernel<<<dim3(UBD / 64, 12), 256, 0, stream>>>(dproto, sproto,
                                                                usage, PT);
  // zero raw-sum targets (MDR+MSIG contiguous) and scatter accumulators
  hipMemsetAsync(out, 0, (size_t)OFF_MCONF * sizeof(float), stream);
  hipMemsetAsync(sum_w, 0, 2u * UBD * sizeof(float), stream);

  detect_mask_kernel<<<1, 64, 0, stream>>>(wm, flag);
  row_prep_kernel<<<NR, 256, 0, stream>>>(q_u, q_b, usage, ema, wm, flag,
                                          denom, base_raw, wgtb, cellid, mrow);
  mfma_gemm_kernel<<<768, 256, 0, stream>>>(q_u, qb16, PT, out);
  epilogue_kernel<<<NR, 256, 0, stream>>>(q_sig, denom, base_raw, out);

  // PT/qb16 consumed; now zero the proto accumulator regions and run updates
  hipMemsetAsync(out + OFF_NDP, 0, (size_t)UBD * (RD + SD) * sizeof(float), stream);
  scatter_kernel<<<NR, 256, 0, stream>>>(dtg, q_sig, wgtb, cellid, mrow,
                                         out + OFF_NDP, out + OFF_NSP, sum_w, cnt);
  ema_proto_kernel<<<4096, 256, 0, stream>>>(dproto, sproto, sum_w, cnt,
                                             out + OFF_NDP, out + OFF_NSP);
  ema_small_kernel<<<UBD / 256, 256, 0, stream>>>(ema, usage, sum_w, cnt,
                                                  out + OFF_NEC, out + OFF_NUS);
  stats_kernel<<<1, 256, 0, stream>>>(cnt, out + OFF_NUS, out + OFF_SCAL);
}

// Round 5
// 280.971 us; speedup vs baseline: 1.4880x; 1.4880x over previous
//
#include <hip/hip_runtime.h>
#include <hip/hip_bf16.h>
#include <hip/hip_fp8.h>
#include <math.h>

#define NR 4096
#define UD 64
#define BD 256
#define SD 256
#define RD 512
#define UBD 16384
#define DECAY 0.99f

typedef unsigned char u8;
typedef unsigned short ushort_t;
typedef __attribute__((ext_vector_type(4))) float f32x4;

// output offsets (in floats), concatenated in reference return order
#define OFF_MDR   0ull          // memory_delta_rule   [4096,512]
#define OFF_MSIG  2097152ull    // memory_signature    [4096,256]
#define OFF_MCONF 3145728ull    // memory_conf         [4096,1]
#define OFF_NDP   3149824ull    // new_delta_proto     [64,256,512]
#define OFF_NSP   11538432ull   // new_signature_proto [64,256,256]
#define OFF_NEC   15732736ull   // new_ema_conf        [64,256]
#define OFF_NUS   15749120ull   // new_usage           [64,256]
#define OFF_SCAL  15765504ull   // write_rate, usage_fraction, usage_entropy

static __device__ __forceinline__ u8 f2e4m3(float x) {
  __hip_fp8_e4m3 h(x);        // OCP e4m3fn, RNE+sat
  return (u8)h.__x;
}

static __device__ __forceinline__ void gll16(const void* g, void* l) {
  __builtin_amdgcn_global_load_lds(
      (const __attribute__((address_space(1))) unsigned int*)g,
      (__attribute__((address_space(3))) unsigned int*)l, 16, 0, 0);
}

// ---------------------------------------------------------------------------
// Detect how write_mask (jax bool) was delivered: int32 (2), float32 (1), byte (0)
__global__ void detect_mask_kernel(const unsigned char* __restrict__ wm,
                                   int* __restrict__ flag)
{
  if (threadIdx.x != 0 || blockIdx.x != 0) return;
  const int*   wi = (const int*)wm;
  const float* wf = (const float*)wm;
  bool is_i32 = true, is_f32 = true;
  for (int i = 0; i < 16; ++i) {
    int v = wi[i];
    if (v != 0 && v != 1) is_i32 = false;
    float f = wf[i];
    if (f != 0.f && f != 1.f) is_f32 = false;
  }
  *flag = is_i32 ? 2 : (is_f32 ? 1 : 0);
}

// ---------------------------------------------------------------------------
// Per-row: denom, unnormalized base_conf, argmax(q_u), argmax(q_b), wgt, cell, m
__global__ __launch_bounds__(256) void row_prep_kernel(
    const float* __restrict__ q_u, const float* __restrict__ q_b,
    const float* __restrict__ usage, const float* __restrict__ ema,
    const unsigned char* __restrict__ wm, const int* __restrict__ flag,
    float* __restrict__ denom, float* __restrict__ base_raw,
    float* __restrict__ wgt, int* __restrict__ cellid, float* __restrict__ mrow)
{
  const int n = blockIdx.x;
  const int t = threadIdx.x;
  __shared__ float s_qu[UD];
  __shared__ float r1[256];
  __shared__ float r2[256];
  __shared__ int   ri[256];
  if (t < UD) s_qu[t] = q_u[(size_t)n * UD + t];
  __syncthreads();
  const float qb = q_b[(size_t)n * BD + t];
  float accd = 0.f, accc = 0.f;
  #pragma unroll 4
  for (int u = 0; u < UD; ++u) {
    const int idx = u * BD + t;
    if (usage[idx] > 0.f) {
      const float qu = s_qu[u];
      accd += qu;
      accc += qu * ema[idx];
    }
  }
  accd *= qb; accc *= qb;
  r1[t] = accd; r2[t] = accc;
  __syncthreads();
  for (int s = 128; s > 0; s >>= 1) {
    if (t < s) { r1[t] += r1[t + s]; r2[t] += r2[t + s]; }
    __syncthreads();
  }
  const float dsum = r1[0];
  const float csum = r2[0];
  __syncthreads();
  // argmax over q_b (first-index tie-break)
  r1[t] = qb; ri[t] = t;
  __syncthreads();
  for (int s = 128; s > 0; s >>= 1) {
    if (t < s) {
      float v2 = r1[t + s]; int i2 = ri[t + s];
      if (v2 > r1[t] || (v2 == r1[t] && i2 < ri[t])) { r1[t] = v2; ri[t] = i2; }
    }
    __syncthreads();
  }
  const float bmax = r1[0]; const int bidx = ri[0];
  __syncthreads();
  // argmax over q_u
  r1[t] = (t < UD) ? s_qu[t] : -1e30f; ri[t] = t;
  __syncthreads();
  for (int s = 128; s > 0; s >>= 1) {
    if (t < s) {
      float v2 = r1[t + s]; int i2 = ri[t + s];
      if (v2 > r1[t] || (v2 == r1[t] && i2 < ri[t])) { r1[t] = v2; ri[t] = i2; }
    }
    __syncthreads();
  }
  if (t == 0) {
    const float umax = r1[0]; const int uidx = ri[0];
    const int fm = *flag;
    float m;
    if (fm == 2)      m = (((const int*)wm)[n]   != 0)   ? 1.f : 0.f;
    else if (fm == 1) m = (((const float*)wm)[n] != 0.f) ? 1.f : 0.f;
    else              m = (wm[n] != 0) ? 1.f : 0.f;
    denom[n]    = dsum;
    base_raw[n] = csum;
    wgt[n]      = umax * bmax * m;
    cellid[n]   = uidx * BD + bidx;
    mrow[n]     = m;
  }
}

// ---------------------------------------------------------------------------
// q_b -> fp8 e4m3 (A operand of the GEMM)
__global__ __launch_bounds__(256) void qb8_kernel(
    const float* __restrict__ qb, u8* __restrict__ qb8)
{
  const int i = blockIdx.x * 256 + threadIdx.x;   // 262144 threads, 4 elems each
  const float4 v = *(const float4*)(qb + (size_t)i * 4);
  u8 tmp[4] = { f2e4m3(v.x), f2e4m3(v.y), f2e4m3(v.z), f2e4m3(v.w) };
  unsigned int wv; __builtin_memcpy(&wv, tmp, 4);
  *(unsigned int*)(qb8 + (size_t)i * 4) = wv;
}

// ---------------------------------------------------------------------------
// q_u transpose: quT[u][n] f32 (for the per-u-chunk fold in the GEMM)
__global__ __launch_bounds__(256) void qut_kernel(
    const float* __restrict__ qu, float* __restrict__ quT)
{
  __shared__ float s[64][65];
  const int n0 = blockIdx.x * 64;
  const int tid = threadIdx.x;
  #pragma unroll
  for (int i = 0; i < 16; ++i) {
    const int idx = tid + i * 256;
    const int r = idx >> 6, u = idx & 63;
    s[r][u] = qu[(size_t)(n0 + r) * UD + u];
  }
  __syncthreads();
  #pragma unroll
  for (int i = 0; i < 16; ++i) {
    const int idx = tid + i * 256;
    const int u = idx >> 6, r = idx & 63;
    quT[(size_t)u * NR + n0 + r] = s[r][u];
  }
}

// ---------------------------------------------------------------------------
// Masked, TRANSPOSED fp8 proto: PT8[c][k], c in [0,768), k in [0,16384)
__global__ __launch_bounds__(256) void transpose_mask_kernel(
    const float* __restrict__ dproto, const float* __restrict__ sproto,
    const float* __restrict__ usage, u8* __restrict__ PT8)
{
  __shared__ u8 s[64][68];
  const int k0 = blockIdx.x * 64;
  const int rblk = blockIdx.y;       // 0..11
  const float* src; int ld; int c0s;
  if (rblk < 8) { src = dproto; ld = RD; c0s = rblk * 64; }
  else          { src = sproto; ld = SD; c0s = (rblk - 8) * 64; }
  const int tid = threadIdx.x;
  const int kl = tid >> 4;
  const int rl = (tid & 15) * 4;
  #pragma unroll
  for (int i = 0; i < 4; ++i) {
    const int k = kl + i * 16;
    const bool valid = usage[k0 + k] > 0.f;
    const float4 v = *(const float4*)(src + (size_t)(k0 + k) * ld + c0s + rl);
    s[k][rl + 0] = valid ? f2e4m3(v.x) : (u8)0;
    s[k][rl + 1] = valid ? f2e4m3(v.y) : (u8)0;
    s[k][rl + 2] = valid ? f2e4m3(v.z) : (u8)0;
    s[k][rl + 3] = valid ? f2e4m3(v.w) : (u8)0;
  }
  __syncthreads();
  const int rl2 = tid >> 4;
  const int kl2 = (tid & 15) * 4;
  #pragma unroll
  for (int i = 0; i < 4; ++i) {
    const int r = rl2 + i * 16;
    u8 tmp[4] = { s[kl2 + 0][r], s[kl2 + 1][r], s[kl2 + 2][r], s[kl2 + 3][r] };
    unsigned int wv; __builtin_memcpy(&wv, tmp, 4);
    *(unsigned int*)(PT8 + (size_t)(rblk * 64 + r) * UBD + k0 + kl2) = wv;
  }
}

// ---------------------------------------------------------------------------
// fp8 MFMA retrieve GEMM with XCC_ID-based work claiming.
// Craw[n,c] = sum_u quT[u][n] * sum_b qb8[n,b] * PT8[c, u*256+b]
// 128x128 tile, GBK=128, 4 waves (2x2), split-K x4, atomicAdd epilogue.
// A (qb8) staged ONCE (u-invariant, 2x16KB); B double-buffered via
// global_load_lds with pre-swizzled source; one barrier per k-step.
__global__ __launch_bounds__(256, 2) void mfma_gemm_kernel(
    const float* __restrict__ quT, const u8* __restrict__ qb8,
    const u8* __restrict__ PT8, float* __restrict__ out,
    int* __restrict__ tk, int* __restrict__ gf, int* __restrict__ claimed)
{
  __shared__ u8 sA[2][128 * 128];   // two b-halves, staged once
  __shared__ u8 sB[2][128 * 128];   // k-step double buffer
  __shared__ int s_work;
  const int tid = threadIdx.x;

  // ---- work claim: per-XCD tickets (hardware XCC_ID), CAS-steal fallback.
  // Every item claimed exactly once under ANY dispatch policy.
  if (tid == 0) {
    unsigned int xcc;
    asm volatile("s_getreg_b32 %0, hwreg(HW_REG_XCC_ID)" : "=s"(xcc));
    const int x = (int)(xcc & 7u);
    const int t = atomicAdd(&tk[x], 1);
    int w = -1;
    if (t < 96) {
      const int cand = x * 96 + t;
      if (atomicCAS(&claimed[cand], 0, 1) == 0) w = cand;
    }
    while (w < 0) {
      const int g = atomicAdd(gf, 1);
      if (g >= 768) { w = -2; break; }   // unreachable (see claim proof)
      if (atomicCAS(&claimed[g], 0, 1) == 0) w = g;
    }
    s_work = w;
  }
  __syncthreads();
  const int w = s_work;
  if (w < 0) return;

  const int bx = w & 31;            // n-tile 0..31
  const int combo = w >> 5;         // 0..23 (XCD x owns combos [3x, 3x+3))
  const int by = combo >> 2;        // col-tile 0..5
  const int bz = combo & 3;         // k-split 0..3

  const int wid = tid >> 6, lane = tid & 63;
  const int n0 = bx * 128;
  const int kbeg = bz * (UBD / 4);

  float* obase; int ldO; int cc0;
  if (by < 4) { obase = out + OFF_MDR;  ldO = RD; cc0 = by * 128; }
  else        { obase = out + OFF_MSIG; ldO = SD; cc0 = (by - 4) * 128; }
  const int c0 = by * 128;          // PT8 row base

  // ---- staging geometry: wave w stages rows [w*32, w*32+32)
  // LDS linear dest (gll: base + lane*16); source chunk pre-swizzled so the
  // XOR-swizzled read below is the inverse permutation (rule 21).
  const int srowbase = wid * 32;
  const int lrow = lane >> 3;                    // 0..7
  const int csrc = ((lane & 7) ^ lrow) * 16;     // 16B-granule involution
  const u8* gA = qb8 + (size_t)(n0 + srowbase + lrow) * BD + csrc;
  const u8* gB = PT8 + (size_t)(c0 + srowbase + lrow) * UBD + kbeg + csrc;

  // ---- fragment geometry (16x16x32 fp8: row=lane&15, k=(lane>>4)*8+e)
  const int wr = (wid >> 1) * 64, wc = (wid & 1) * 64;
  const int fr = lane & 15;
  const int fk8 = (lane >> 4) * 8;
  const int swz = (fr & 7) << 4;

  int aoff[4], boff[4];
  #pragma unroll
  for (int m = 0; m < 4; ++m) aoff[m] = (wr + m * 16 + fr) * 128;
  #pragma unroll
  for (int nn = 0; nn < 4; ++nn) boff[nn] = (wc + nn * 16 + fr) * 128;

  f32x4 accm[4][4];
  #pragma unroll
  for (int m = 0; m < 4; ++m)
    #pragma unroll
    for (int nn = 0; nn < 4; ++nn)
      accm[m][nn] = (f32x4){0.f, 0.f, 0.f, 0.f};

  // ---- prologue: both A halves + B step0
  #pragma unroll
  for (int i = 0; i < 4; ++i) {
    gll16(gA + (size_t)i * 8 * BD,       &sA[0][(srowbase + i * 8) * 128]);
    gll16(gA + (size_t)i * 8 * BD + 128, &sA[1][(srowbase + i * 8) * 128]);
    gll16(gB + (size_t)i * 8 * UBD,      &sB[0][(srowbase + i * 8) * 128]);
  }
  __syncthreads();

  const float* quTb = quT + n0 + wr + (lane >> 4) * 4;
  const int ubase = kbeg >> 8;

  for (int uc = 0; uc < 16; ++uc) {
    f32x4 accu[4][4];
    #pragma unroll
    for (int half = 0; half < 2; ++half) {
      const int step = uc * 2 + half;           // buffer index == half (&1)
      // issue next B stage into the other buffer (drained by the barrier)
      if (step < 31) {
        const u8* gs = gB + (size_t)(step + 1) * 128;
        #pragma unroll
        for (int i = 0; i < 4; ++i)
          gll16(gs + (size_t)i * 8 * UBD, &sB[half ^ 1][(srowbase + i * 8) * 128]);
      }
      const u8* sa = sA[half];
      const u8* sb = sB[half];
      #pragma unroll
      for (int ks = 0; ks < 4; ++ks) {
        const int ko = (ks * 32 + fk8) ^ swz;
        long av[4], bv[4];
        #pragma unroll
        for (int m = 0; m < 4; ++m)
          av[m] = *(const long*)(sa + aoff[m] + ko);
        #pragma unroll
        for (int nn = 0; nn < 4; ++nn)
          bv[nn] = *(const long*)(sb + boff[nn] + ko);
        #pragma unroll
        for (int m = 0; m < 4; ++m)
          #pragma unroll
          for (int nn = 0; nn < 4; ++nn) {
            if (half == 0 && ks == 0)
              accu[m][nn] = __builtin_amdgcn_mfma_f32_16x16x32_fp8_fp8(
                  av[m], bv[nn], (f32x4){0.f, 0.f, 0.f, 0.f}, 0, 0, 0);
            else
              accu[m][nn] = __builtin_amdgcn_mfma_f32_16x16x32_fp8_fp8(
                  av[m], bv[nn], accu[m][nn], 0, 0, 0);
          }
      }
      __syncthreads();
    }
    // ---- fold exact f32 q_u for this u-chunk
    const float* qp = quTb + (size_t)(ubase + uc) * NR;
    #pragma unroll
    for (int m = 0; m < 4; ++m) {
      const f32x4 qv = *(const f32x4*)(qp + m * 16);
      #pragma unroll
      for (int nn = 0; nn < 4; ++nn)
        accm[m][nn] += qv * accu[m][nn];
    }
  }

  // ---- epilogue: atomic accumulate raw sums (scaled later by 1/denom)
  const int orow = (lane >> 4) * 4;
  #pragma unroll
  for (int m = 0; m < 4; ++m) {
    #pragma unroll
    for (int nn = 0; nn < 4; ++nn) {
      const int c = cc0 + wc + nn * 16 + fr;
      #pragma unroll
      for (int j = 0; j < 4; ++j) {
        const int r = n0 + wr + m * 16 + orow + j;
        atomicAdd(obase + (size_t)r * ldO + c, accm[m][nn][j]);
      }
    }
  }
}

// ---------------------------------------------------------------------------
// Scale raw GEMM sums by 1/denom in place; fuse memory_conf (cosine)
__global__ __launch_bounds__(256) void epilogue_kernel(
    const float* __restrict__ q_sigma, const float* __restrict__ denom,
    const float* __restrict__ base_raw, float* __restrict__ out)
{
  const int n = blockIdx.x;
  const int t = threadIdx.x;
  __shared__ float r1[256], r2[256], r3[256];
  const float d = denom[n];
  const float scale = (d > 0.f) ? (1.f / fmaxf(d, 1e-6f)) : 0.f;
  float* mdr = out + OFF_MDR + (size_t)n * RD;
  mdr[t]       *= scale;
  mdr[t + 256] *= scale;
  float* msig = out + OFF_MSIG + (size_t)n * SD;
  const float s = msig[t] * scale;
  msig[t] = s;
  const float a = q_sigma[(size_t)n * SD + t];
  const float b = s + 1e-6f;
  r1[t] = a * a; r2[t] = b * b; r3[t] = a * b;
  __syncthreads();
  for (int st = 128; st > 0; st >>= 1) {
    if (t < st) { r1[t] += r1[t + st]; r2[t] += r2[t + st]; r3[t] += r3[t + st]; }
    __syncthreads();
  }
  if (t == 0) {
    const float na = fmaxf(sqrtf(r1[0]), 1e-12f);
    const float nb = fmaxf(sqrtf(r2[0]), 1e-12f);
    const float cosv = r3[0] / (na * nb);
    const float agree = 0.5f * (1.f + cosv);
    const float base = (d > 0.f) ? base_raw[n] / fmaxf(d, 1e-6f) : 0.f;
    out[OFF_MCONF + n] = fminf(fmaxf(base * agree, 0.f), 1.f);
  }
}

// ---------------------------------------------------------------------------
// Scatter segment-sums into the (zeroed) new_*_proto output regions + sum_w/cnt
__global__ __launch_bounds__(256) void scatter_kernel(
    const float* __restrict__ dtarget, const float* __restrict__ q_sigma,
    const float* __restrict__ wgt, const int* __restrict__ cellid,
    const float* __restrict__ mrow,
    float* __restrict__ sumd, float* __restrict__ sums,
    float* __restrict__ sum_w, float* __restrict__ cnt)
{
  const int n = blockIdx.x;
  if (mrow[n] == 0.f) return;
  const int t = threadIdx.x;
  const int c = cellid[n];
  const float w = wgt[n];
  atomicAdd(&sumd[(size_t)c * RD + t],       dtarget[(size_t)n * RD + t] * w);
  atomicAdd(&sumd[(size_t)c * RD + t + 256], dtarget[(size_t)n * RD + t + 256] * w);
  atomicAdd(&sums[(size_t)c * SD + t],       q_sigma[(size_t)n * SD + t] * w);
  if (t == 0) { atomicAdd(&sum_w[c], w); atomicAdd(&cnt[c], 1.f); }
}

// ---------------------------------------------------------------------------
// In-place EMA transform of proto sums -> new protos
__global__ __launch_bounds__(256) void ema_proto_kernel(
    const float* __restrict__ dproto, const float* __restrict__ sproto,
    const float* __restrict__ sum_w, const float* __restrict__ cnt,
    float* __restrict__ outd, float* __restrict__ outs)
{
  const size_t nd = (size_t)UBD * RD;          // 8388608
  const size_t total = nd + (size_t)UBD * SD;  // 12582912
  for (size_t i = (size_t)blockIdx.x * 256 + threadIdx.x; i < total;
       i += (size_t)gridDim.x * 256) {
    if (i < nd) {
      const int cell = (int)(i >> 9);
      const float c = cnt[cell];
      float v;
      if (c > 0.f) {
        const float cs = fmaxf(sum_w[cell], 1e-6f);
        v = DECAY * dproto[i] + (1.f - DECAY) * (outd[i] / cs);
      } else v = dproto[i];
      outd[i] = v;
    } else {
      const size_t j = i - nd;
      const int cell = (int)(j >> 8);
      const float c = cnt[cell];
      float v;
      if (c > 0.f) {
        const float cs = fmaxf(sum_w[cell], 1e-6f);
        v = DECAY * sproto[j] + (1.f - DECAY) * (outs[j] / cs);
      } else v = sproto[j];
      outs[j] = v;
    }
  }
}

// ---------------------------------------------------------------------------
__global__ __launch_bounds__(256) void ema_small_kernel(
    const float* __restrict__ ema, const float* __restrict__ usage,
    const float* __restrict__ sum_w, const float* __restrict__ cnt,
    float* __restrict__ out_ec, float* __restrict__ out_us)
{
  const int i = blockIdx.x * 256 + threadIdx.x;
  if (i < UBD) {
    const float c = cnt[i];
    const float cm = sum_w[i] / fmaxf(c, 1.f);
    out_ec[i] = (c > 0.f) ? DECAY * ema[i] + (1.f - DECAY) * cm : ema[i];
    out_us[i] = usage[i] + c;
  }
}

// ---------------------------------------------------------------------------
// write_rate, usage_fraction, usage_entropy (single block)
__global__ __launch_bounds__(256) void stats_kernel(
    const float* __restrict__ cnt, const float* __restrict__ new_us,
    float* __restrict__ out_scalars)
{
  const int t = threadIdx.x;
  __shared__ float r1[256], r2[256], r3[256];
  float scnt = 0.f, snz = 0.f, sus = 0.f;
  for (int i = t; i < UBD; i += 256) {
    const float c = cnt[i]; scnt += c;
    const float u = new_us[i];
    if (u > 0.f) snz += 1.f;
    sus += u;
  }
  r1[t] = scnt; r2[t] = snz; r3[t] = sus;
  __syncthreads();
  for (int s = 128; s > 0; s >>= 1) {
    if (t < s) { r1[t] += r1[t + s]; r2[t] += r2[t + s]; r3[t] += r3[t + s]; }
    __syncthreads();
  }
  const float total_cnt = r1[0], total_nz = r2[0], total_us = r3[0];
  __syncthreads();
  const float S = fmaxf(total_us, 1e-6f);
  float ent = 0.f;
  for (int i = t; i < UBD; i += 256) {
    const float d = new_us[i] / S;
    ent += d * logf(d + 1e-6f);
  }
  r1[t] = ent;
  __syncthreads();
  for (int s = 128; s > 0; s >>= 1) {
    if (t < s) { r1[t] += r1[t + s]; }
    __syncthreads();
  }
  if (t == 0) {
    out_scalars[0] = total_cnt / (float)NR;
    out_scalars[1] = total_nz / (float)UBD;
    out_scalars[2] = -r1[0] / 9.70406053f;   // ln(16384)
  }
}

// ---------------------------------------------------------------------------
extern "C" void kernel_launch(void* const* d_in, const int* in_sizes, int n_in,
                              void* d_out, int out_size, void* d_ws, size_t ws_size,
                              hipStream_t stream)
{
  const float* q_u    = (const float*)d_in[0];
  const float* q_b    = (const float*)d_in[1];
  const float* q_sig  = (const float*)d_in[2];
  const float* dtg    = (const float*)d_in[3];
  const unsigned char* wm = (const unsigned char*)d_in[4];
  const float* dproto = (const float*)d_in[5];
  const float* sproto = (const float*)d_in[6];
  const float* ema    = (const float*)d_in[7];
  const float* usage  = (const float*)d_in[8];
  float* out = (float*)d_out;

  float* wsf = (float*)d_ws;
  int*   wsi = (int*)d_ws;
  int*   flag     = wsi;                       // [16]
  float* denom    = wsf + 16;                  // [4096]
  float* base_raw = wsf + 16 + 4096;           // [4096]
  float* wgtb     = wsf + 16 + 8192;           // [4096]
  int*   cellid   = wsi + 16 + 12288;          // [4096]
  float* mrow     = wsf + 16 + 16384;          // [4096]
  float* sum_w    = wsf + 20496;               // [16384]
  float* cnt      = wsf + 20496 + 16384;       // [16384]
  int*   tk       = wsi + 53264;               // [8]
  int*   gf       = wsi + 53272;               // [1] (+7 pad)
  int*   claimed  = wsi + 53280;               // [768]

  // PT8 (12.6 MB) + qb8 (1 MB) + quT (1 MB) park in the NDP output region,
  // which is rewritten only after the GEMM has consumed them.
  u8*    PT8 = (u8*)(out + OFF_NDP);
  u8*    qb8 = PT8 + (size_t)768 * UBD;
  float* quT = (float*)(qb8 + (size_t)NR * BD);

  qb8_kernel<<<(NR * BD / 4) / 256, 256, 0, stream>>>(q_b, qb8);
  qut_kernel<<<NR / 64, 256, 0, stream>>>(q_u, quT);
  transpose_mask_kernel<<<dim3(UBD / 64, 12), 256, 0, stream>>>(dproto, sproto,
                                                                usage, PT8);
  // zero raw-sum targets (MDR+MSIG) and sum_w/cnt/tk/gf/claimed (contiguous)
  hipMemsetAsync(out, 0, (size_t)OFF_MCONF * sizeof(float), stream);
  hipMemsetAsync(sum_w, 0, (2u * UBD + 16 + 768) * sizeof(float), stream);

  detect_mask_kernel<<<1, 64, 0, stream>>>(wm, flag);
  row_prep_kernel<<<NR, 256, 0, stream>>>(q_u, q_b, usage, ema, wm, flag,
                                          denom, base_raw, wgtb, cellid, mrow);
  mfma_gemm_kernel<<<768, 256, 0, stream>>>(quT, qb8, PT8, out, tk, gf, claimed);
  epilogue_kernel<<<NR, 256, 0, stream>>>(q_sig, denom, base_raw, out);

  // precompute buffers consumed; zero proto accumulators and run the update path
  hipMemsetAsync(out + OFF_NDP, 0, (size_t)UBD * (RD + SD) * sizeof(float), stream);
  scatter_kernel<<<NR, 256, 0, stream>>>(dtg, q_sig, wgtb, cellid, mrow,
                                         out + OFF_NDP, out + OFF_NSP, sum_w, cnt);
  ema_proto_kernel<<<4096, 256, 0, stream>>>(dproto, sproto, sum_w, cnt,
                                             out + OFF_NDP, out + OFF_NSP);
  ema_small_kernel<<<UBD / 256, 256, 0, stream>>>(ema, usage, sum_w, cnt,
                                                  out + OFF_NEC, out + OFF_NUS);
  stats_kernel<<<1, 256, 0, stream>>>(cnt, out + OFF_NUS, out + OFF_SCAL);
}

// Round 6
// 278.261 us; speedup vs baseline: 1.5025x; 1.0097x over previous
//
#include <hip/hip_runtime.h>
#include <hip/hip_fp8.h>
#include <math.h>

#define NR 4096
#define UD 64
#define BD 256
#define SD 256
#define RD 512
#define UBD 16384
#define DECAY 0.99f

typedef unsigned char u8;
typedef __attribute__((ext_vector_type(4))) float f32x4;
typedef __attribute__((ext_vector_type(2))) long longx2;

// output offsets (in floats), concatenated in reference return order
#define OFF_MDR   0ull          // memory_delta_rule   [4096,512]
#define OFF_MSIG  2097152ull    // memory_signature    [4096,256]
#define OFF_MCONF 3145728ull    // memory_conf         [4096,1]
#define OFF_NDP   3149824ull    // new_delta_proto     [64,256,512]
#define OFF_NSP   11538432ull   // new_signature_proto [64,256,256]
#define OFF_NEC   15732736ull   // new_ema_conf        [64,256]
#define OFF_NUS   15749120ull   // new_usage           [64,256]
#define OFF_SCAL  15765504ull   // write_rate, usage_fraction, usage_entropy

static __device__ __forceinline__ u8 f2e4m3(float x) {
  __hip_fp8_e4m3 h(x);        // OCP e4m3fn, RNE+sat
  return (u8)h.__x;
}

static __device__ __forceinline__ void gll16(const void* g, void* l) {
  __builtin_amdgcn_global_load_lds(
      (const __attribute__((address_space(1))) unsigned int*)g,
      (__attribute__((address_space(3))) unsigned int*)l, 16, 0, 0);
}

// k-order permutation within a 64-block: b = ks8*32 + kg*8 + e  ->  kg*16 + ks8*8 + e
// (x must be in [0,64))
static __device__ __forceinline__ int perm64(int x) {
  return (((x >> 3) & 3) << 4) | (((x >> 5) & 1) << 3) | (x & 7);
}

// ---------------------------------------------------------------------------
// Per-row: denom, unnormalized base_conf, argmax(q_u), argmax(q_b), wgt, cell, m
// (write_mask dtype detection inlined: int32 / float32 / byte)
__global__ __launch_bounds__(256) void row_prep_kernel(
    const float* __restrict__ q_u, const float* __restrict__ q_b,
    const float* __restrict__ usage, const float* __restrict__ ema,
    const unsigned char* __restrict__ wm,
    float* __restrict__ denom, float* __restrict__ base_raw,
    float* __restrict__ wgt, int* __restrict__ cellid, float* __restrict__ mrow)
{
  const int n = blockIdx.x;
  const int t = threadIdx.x;
  __shared__ float s_qu[UD];
  __shared__ float r1[256];
  __shared__ float r2[256];
  __shared__ int   ri[256];
  if (t < UD) s_qu[t] = q_u[(size_t)n * UD + t];
  __syncthreads();
  const float qb = q_b[(size_t)n * BD + t];
  float accd = 0.f, accc = 0.f;
  #pragma unroll 4
  for (int u = 0; u < UD; ++u) {
    const int idx = u * BD + t;
    if (usage[idx] > 0.f) {
      const float qu = s_qu[u];
      accd += qu;
      accc += qu * ema[idx];
    }
  }
  accd *= qb; accc *= qb;
  r1[t] = accd; r2[t] = accc;
  __syncthreads();
  for (int s = 128; s > 0; s >>= 1) {
    if (t < s) { r1[t] += r1[t + s]; r2[t] += r2[t + s]; }
    __syncthreads();
  }
  const float dsum = r1[0];
  const float csum = r2[0];
  __syncthreads();
  // argmax over q_b (first-index tie-break)
  r1[t] = qb; ri[t] = t;
  __syncthreads();
  for (int s = 128; s > 0; s >>= 1) {
    if (t < s) {
      float v2 = r1[t + s]; int i2 = ri[t + s];
      if (v2 > r1[t] || (v2 == r1[t] && i2 < ri[t])) { r1[t] = v2; ri[t] = i2; }
    }
    __syncthreads();
  }
  const float bmax = r1[0]; const int bidx = ri[0];
  __syncthreads();
  // argmax over q_u
  r1[t] = (t < UD) ? s_qu[t] : -1e30f; ri[t] = t;
  __syncthreads();
  for (int s = 128; s > 0; s >>= 1) {
    if (t < s) {
      float v2 = r1[t + s]; int i2 = ri[t + s];
      if (v2 > r1[t] || (v2 == r1[t] && i2 < ri[t])) { r1[t] = v2; ri[t] = i2; }
    }
    __syncthreads();
  }
  if (t == 0) {
    const float umax = r1[0]; const int uidx = ri[0];
    // inline write_mask dtype detect
    const int*   wi = (const int*)wm;
    const float* wf = (const float*)wm;
    bool is_i32 = true, is_f32 = true;
    #pragma unroll
    for (int i = 0; i < 16; ++i) {
      int v = wi[i];
      if (v != 0 && v != 1) is_i32 = false;
      float f = wf[i];
      if (f != 0.f && f != 1.f) is_f32 = false;
    }
    float m;
    if (is_i32)      m = (wi[n] != 0)   ? 1.f : 0.f;
    else if (is_f32) m = (wf[n] != 0.f) ? 1.f : 0.f;
    else             m = (wm[n] != 0)   ? 1.f : 0.f;
    denom[n]    = dsum;
    base_raw[n] = csum;
    wgt[n]      = umax * bmax * m;
    cellid[n]   = uidx * BD + bidx;
    mrow[n]     = m;
  }
}

// ---------------------------------------------------------------------------
// Fused prep: blocks [0,1024): q_b -> fp8 (k-permuted); blocks [1024,1088): quT
__global__ __launch_bounds__(256) void prep_kernel(
    const float* __restrict__ qb, const float* __restrict__ qu,
    u8* __restrict__ qb8, float* __restrict__ quT)
{
  if (blockIdx.x < 1024) {
    const int i = blockIdx.x * 256 + threadIdx.x;   // 4 consecutive b each
    const int idx = i * 4;
    const int row = idx >> 8;
    const int b   = idx & 255;
    const float4 v = *(const float4*)(qb + (size_t)idx);
    u8 tmp[4] = { f2e4m3(v.x), f2e4m3(v.y), f2e4m3(v.z), f2e4m3(v.w) };
    unsigned int wv; __builtin_memcpy(&wv, tmp, 4);
    const int nb = (b & ~63) | perm64(b & 63);
    *(unsigned int*)(qb8 + (size_t)row * BD + nb) = wv;
  } else {
    __shared__ float s[64][65];
    const int n0 = (blockIdx.x - 1024) * 64;
    const int tid = threadIdx.x;
    #pragma unroll
    for (int i = 0; i < 16; ++i) {
      const int idx = tid + i * 256;
      const int r = idx >> 6, u = idx & 63;
      s[r][u] = qu[(size_t)(n0 + r) * UD + u];
    }
    __syncthreads();
    #pragma unroll
    for (int i = 0; i < 16; ++i) {
      const int idx = tid + i * 256;
      const int u = idx >> 6, r = idx & 63;
      quT[(size_t)u * NR + n0 + r] = s[r][u];
    }
  }
}

// ---------------------------------------------------------------------------
// Masked, TRANSPOSED, k-permuted fp8 proto: PT8[c][k'], c in [0,768)
__global__ __launch_bounds__(256) void transpose_mask_kernel(
    const float* __restrict__ dproto, const float* __restrict__ sproto,
    const float* __restrict__ usage, u8* __restrict__ PT8)
{
  __shared__ u8 s[64][68];
  const int k0 = blockIdx.x * 64;
  const int rblk = blockIdx.y;       // 0..11
  const float* src; int ld; int c0s;
  if (rblk < 8) { src = dproto; ld = RD; c0s = rblk * 64; }
  else          { src = sproto; ld = SD; c0s = (rblk - 8) * 64; }
  const int tid = threadIdx.x;
  const int kl = tid >> 4;
  const int rl = (tid & 15) * 4;
  #pragma unroll
  for (int i = 0; i < 4; ++i) {
    const int k = kl + i * 16;
    const bool valid = usage[k0 + k] > 0.f;
    const float4 v = *(const float4*)(src + (size_t)(k0 + k) * ld + c0s + rl);
    s[k][rl + 0] = valid ? f2e4m3(v.x) : (u8)0;
    s[k][rl + 1] = valid ? f2e4m3(v.y) : (u8)0;
    s[k][rl + 2] = valid ? f2e4m3(v.z) : (u8)0;
    s[k][rl + 3] = valid ? f2e4m3(v.w) : (u8)0;
  }
  __syncthreads();
  const int rl2 = tid >> 4;
  const int kl2 = (tid & 15) * 4;
  #pragma unroll
  for (int i = 0; i < 4; ++i) {
    const int r = rl2 + i * 16;
    u8 tmp[4] = { s[kl2 + 0][r], s[kl2 + 1][r], s[kl2 + 2][r], s[kl2 + 3][r] };
    unsigned int wv; __builtin_memcpy(&wv, tmp, 4);
    *(unsigned int*)(PT8 + (size_t)(rblk * 64 + r) * UBD + k0 + perm64(kl2)) = wv;
  }
}

// ---------------------------------------------------------------------------
// fp8 MFMA retrieve GEMM, XCC_ID work claiming, b128 fragment reads.
// k-permuted operands: one ds_read_b128 = two MFMA k-steps; granule swizzle
// slot' = slot ^ (row&7) applied via gll SOURCE (LDS dest linear) -> balanced.
__global__ __launch_bounds__(256, 2) void mfma_gemm_kernel(
    const float* __restrict__ quT, const u8* __restrict__ qb8,
    const u8* __restrict__ PT8, float* __restrict__ out,
    int* __restrict__ tk, int* __restrict__ gf, int* __restrict__ claimed)
{
  __shared__ u8 sA[2][128 * 128];   // [b-half][row][128B], staged once
  __shared__ u8 sB[2][128 * 128];   // k-chunk double buffer
  __shared__ int s_work;
  const int tid = threadIdx.x;

  // ---- work claim: per-XCD tickets (hardware XCC_ID), CAS-steal fallback
  if (tid == 0) {
    unsigned int xcc;
    asm volatile("s_getreg_b32 %0, hwreg(HW_REG_XCC_ID)" : "=s"(xcc));
    const int x = (int)(xcc & 7u);
    const int t = atomicAdd(&tk[x], 1);
    int w = -1;
    if (t < 96) {
      const int cand = x * 96 + t;
      if (atomicCAS(&claimed[cand], 0, 1) == 0) w = cand;
    }
    while (w < 0) {
      const int g = atomicAdd(gf, 1);
      if (g >= 768) { w = -2; break; }
      if (atomicCAS(&claimed[g], 0, 1) == 0) w = g;
    }
    s_work = w;
  }
  __syncthreads();
  const int w = s_work;
  if (w < 0) return;

  const int bx = w & 31;            // n-tile 0..31
  const int combo = w >> 5;         // 0..23 (XCD x owns combos [3x, 3x+3))
  const int by = combo >> 2;        // col-tile 0..5
  const int bz = combo & 3;         // k-split 0..3

  const int wid = tid >> 6, lane = tid & 63;
  const int n0 = bx * 128;
  const int kbeg = bz * (UBD / 4);

  float* obase; int ldO; int cc0;
  if (by < 4) { obase = out + OFF_MDR;  ldO = RD; cc0 = by * 128; }
  else        { obase = out + OFF_MSIG; ldO = SD; cc0 = (by - 4) * 128; }
  const int c0 = by * 128;          // PT8 row base

  // ---- staging lane geometry (8 rows x 8 slots per 1KB gll call)
  const int lrow = lane >> 3;                    // 0..7
  const int csrc = ((lane & 7) ^ lrow) * 16;     // source granule pre-swizzle
  const u8* gA = qb8 + (size_t)(n0 + lrow) * BD + csrc;
  const u8* gB = PT8 + (size_t)(c0 + lrow) * UBD + csrc + kbeg;

  // ---- fragment geometry
  const int wr = (wid >> 1) * 64, wc = (wid & 1) * 64;
  const int fr = lane & 15;
  const int kg = lane >> 4;
  const int swz = fr & 7;
  int aoff[4], boff[4];
  #pragma unroll
  for (int m = 0; m < 4; ++m) aoff[m] = (wr + m * 16 + fr) * 128;
  #pragma unroll
  for (int nn = 0; nn < 4; ++nn) boff[nn] = (wc + nn * 16 + fr) * 128;
  int sloth[2];
  #pragma unroll
  for (int bq = 0; bq < 2; ++bq) sloth[bq] = ((bq * 4 + kg) ^ swz) * 16;

  f32x4 accm[4][4];
  #pragma unroll
  for (int m = 0; m < 4; ++m)
    #pragma unroll
    for (int nn = 0; nn < 4; ++nn)
      accm[m][nn] = (f32x4){0.f, 0.f, 0.f, 0.f};

  // ---- prologue: both A halves + B chunk 0
  #pragma unroll
  for (int i = 0; i < 4; ++i) {
    const int ro = wid * 32 + i * 8;
    gll16(gA + (size_t)ro * BD,       &sA[0][ro * 128]);
    gll16(gA + (size_t)ro * BD + 128, &sA[1][ro * 128]);
    gll16(gB + (size_t)ro * UBD,      &sB[0][ro * 128]);
  }
  __syncthreads();

  const float* quTb = quT + n0 + wr + kg * 4;
  const int ubase = kbeg >> 8;

  for (int uc = 0; uc < 16; ++uc) {
    f32x4 accu[4][4];
    #pragma unroll
    for (int half = 0; half < 2; ++half) {
      const int ci = uc * 2 + half;
      // issue next B chunk into the other buffer (drained by the barrier)
      if (ci < 31) {
        const u8* gs = gB + (size_t)(ci + 1) * 128;
        #pragma unroll
        for (int i = 0; i < 4; ++i) {
          const int ro = wid * 32 + i * 8;
          gll16(gs + (size_t)ro * UBD, &sB[half ^ 1][ro * 128]);
        }
      }
      const u8* sa = sA[half];
      const u8* sb = sB[half];
      #pragma unroll
      for (int bq = 0; bq < 2; ++bq) {
        longx2 av[4], bv[4];
        #pragma unroll
        for (int m = 0; m < 4; ++m)
          av[m] = *(const longx2*)(sa + aoff[m] + sloth[bq]);
        #pragma unroll
        for (int nn = 0; nn < 4; ++nn)
          bv[nn] = *(const longx2*)(sb + boff[nn] + sloth[bq]);
        #pragma unroll
        for (int m = 0; m < 4; ++m)
          #pragma unroll
          for (int nn = 0; nn < 4; ++nn) {
            if (half == 0 && bq == 0)
              accu[m][nn] = __builtin_amdgcn_mfma_f32_16x16x32_fp8_fp8(
                  av[m].x, bv[nn].x, (f32x4){0.f, 0.f, 0.f, 0.f}, 0, 0, 0);
            else
              accu[m][nn] = __builtin_amdgcn_mfma_f32_16x16x32_fp8_fp8(
                  av[m].x, bv[nn].x, accu[m][nn], 0, 0, 0);
            accu[m][nn] = __builtin_amdgcn_mfma_f32_16x16x32_fp8_fp8(
                av[m].y, bv[nn].y, accu[m][nn], 0, 0, 0);
          }
      }
      __syncthreads();
    }
    // ---- fold exact f32 q_u for this u-chunk
    const float* qp = quTb + (size_t)(ubase + uc) * NR;
    #pragma unroll
    for (int m = 0; m < 4; ++m) {
      const f32x4 qv = *(const f32x4*)(qp + m * 16);
      #pragma unroll
      for (int nn = 0; nn < 4; ++nn)
        accm[m][nn] += qv * accu[m][nn];
    }
  }

  // ---- epilogue: atomic accumulate raw sums (scaled later by 1/denom)
  #pragma unroll
  for (int m = 0; m < 4; ++m) {
    #pragma unroll
    for (int nn = 0; nn < 4; ++nn) {
      const int c = cc0 + wc + nn * 16 + fr;
      #pragma unroll
      for (int j = 0; j < 4; ++j) {
        const int r = n0 + wr + m * 16 + kg * 4 + j;
        atomicAdd(obase + (size_t)r * ldO + c, accm[m][nn][j]);
      }
    }
  }
}

// ---------------------------------------------------------------------------
// Scale raw GEMM sums by 1/denom in place; fuse memory_conf (cosine)
__global__ __launch_bounds__(256) void epilogue_kernel(
    const float* __restrict__ q_sigma, const float* __restrict__ denom,
    const float* __restrict__ base_raw, float* __restrict__ out)
{
  const int n = blockIdx.x;
  const int t = threadIdx.x;
  __shared__ float r1[256], r2[256], r3[256];
  const float d = denom[n];
  const float scale = (d > 0.f) ? (1.f / fmaxf(d, 1e-6f)) : 0.f;
  float* mdr = out + OFF_MDR + (size_t)n * RD;
  mdr[t]       *= scale;
  mdr[t + 256] *= scale;
  float* msig = out + OFF_MSIG + (size_t)n * SD;
  const float s = msig[t] * scale;
  msig[t] = s;
  const float a = q_sigma[(size_t)n * SD + t];
  const float b = s + 1e-6f;
  r1[t] = a * a; r2[t] = b * b; r3[t] = a * b;
  __syncthreads();
  for (int st = 128; st > 0; st >>= 1) {
    if (t < st) { r1[t] += r1[t + st]; r2[t] += r2[t + st]; r3[t] += r3[t + st]; }
    __syncthreads();
  }
  if (t == 0) {
    const float na = fmaxf(sqrtf(r1[0]), 1e-12f);
    const float nb = fmaxf(sqrtf(r2[0]), 1e-12f);
    const float cosv = r3[0] / (na * nb);
    const float agree = 0.5f * (1.f + cosv);
    const float base = (d > 0.f) ? base_raw[n] / fmaxf(d, 1e-6f) : 0.f;
    out[OFF_MCONF + n] = fminf(fmaxf(base * agree, 0.f), 1.f);
  }
}

// ---------------------------------------------------------------------------
// Scatter segment-sums into the (zeroed) new_*_proto output regions + sum_w/cnt
__global__ __launch_bounds__(256) void scatter_kernel(
    const float* __restrict__ dtarget, const float* __restrict__ q_sigma,
    const float* __restrict__ wgt, const int* __restrict__ cellid,
    const float* __restrict__ mrow,
    float* __restrict__ sumd, float* __restrict__ sums,
    float* __restrict__ sum_w, float* __restrict__ cnt)
{
  const int n = blockIdx.x;
  if (mrow[n] == 0.f) return;
  const int t = threadIdx.x;
  const int c = cellid[n];
  const float w = wgt[n];
  atomicAdd(&sumd[(size_t)c * RD + t],       dtarget[(size_t)n * RD + t] * w);
  atomicAdd(&sumd[(size_t)c * RD + t + 256], dtarget[(size_t)n * RD + t + 256] * w);
  atomicAdd(&sums[(size_t)c * SD + t],       q_sigma[(size_t)n * SD + t] * w);
  if (t == 0) { atomicAdd(&sum_w[c], w); atomicAdd(&cnt[c], 1.f); }
}

// ---------------------------------------------------------------------------
// In-place EMA transform of proto sums -> new protos
__global__ __launch_bounds__(256) void ema_proto_kernel(
    const float* __restrict__ dproto, const float* __restrict__ sproto,
    const float* __restrict__ sum_w, const float* __restrict__ cnt,
    float* __restrict__ outd, float* __restrict__ outs)
{
  const size_t nd = (size_t)UBD * RD;          // 8388608
  const size_t total = nd + (size_t)UBD * SD;  // 12582912
  for (size_t i = (size_t)blockIdx.x * 256 + threadIdx.x; i < total;
       i += (size_t)gridDim.x * 256) {
    if (i < nd) {
      const int cell = (int)(i >> 9);
      const float c = cnt[cell];
      float v;
      if (c > 0.f) {
        const float cs = fmaxf(sum_w[cell], 1e-6f);
        v = DECAY * dproto[i] + (1.f - DECAY) * (outd[i] / cs);
      } else v = dproto[i];
      outd[i] = v;
    } else {
      const size_t j = i - nd;
      const int cell = (int)(j >> 8);
      const float c = cnt[cell];
      float v;
      if (c > 0.f) {
        const float cs = fmaxf(sum_w[cell], 1e-6f);
        v = DECAY * sproto[j] + (1.f - DECAY) * (outs[j] / cs);
      } else v = sproto[j];
      outs[j] = v;
    }
  }
}

// ---------------------------------------------------------------------------
__global__ __launch_bounds__(256) void ema_small_kernel(
    const float* __restrict__ ema, const float* __restrict__ usage,
    const float* __restrict__ sum_w, const float* __restrict__ cnt,
    float* __restrict__ out_ec, float* __restrict__ out_us)
{
  const int i = blockIdx.x * 256 + threadIdx.x;
  if (i < UBD) {
    const float c = cnt[i];
    const float cm = sum_w[i] / fmaxf(c, 1.f);
    out_ec[i] = (c > 0.f) ? DECAY * ema[i] + (1.f - DECAY) * cm : ema[i];
    out_us[i] = usage[i] + c;
  }
}

// ---------------------------------------------------------------------------
// write_rate, usage_fraction, usage_entropy (single block)
__global__ __launch_bounds__(256) void stats_kernel(
    const float* __restrict__ cnt, const float* __restrict__ new_us,
    float* __restrict__ out_scalars)
{
  const int t = threadIdx.x;
  __shared__ float r1[256], r2[256], r3[256];
  float scnt = 0.f, snz = 0.f, sus = 0.f;
  for (int i = t; i < UBD; i += 256) {
    const float c = cnt[i]; scnt += c;
    const float u = new_us[i];
    if (u > 0.f) snz += 1.f;
    sus += u;
  }
  r1[t] = scnt; r2[t] = snz; r3[t] = sus;
  __syncthreads();
  for (int s = 128; s > 0; s >>= 1) {
    if (t < s) { r1[t] += r1[t + s]; r2[t] += r2[t + s]; r3[t] += r3[t + s]; }
    __syncthreads();
  }
  const float total_cnt = r1[0], total_nz = r2[0], total_us = r3[0];
  __syncthreads();
  const float S = fmaxf(total_us, 1e-6f);
  float ent = 0.f;
  for (int i = t; i < UBD; i += 256) {
    const float d = new_us[i] / S;
    ent += d * logf(d + 1e-6f);
  }
  r1[t] = ent;
  __syncthreads();
  for (int s = 128; s > 0; s >>= 1) {
    if (t < s) { r1[t] += r1[t + s]; }
    __syncthreads();
  }
  if (t == 0) {
    out_scalars[0] = total_cnt / (float)NR;
    out_scalars[1] = total_nz / (float)UBD;
    out_scalars[2] = -r1[0] / 9.70406053f;   // ln(16384)
  }
}

// ---------------------------------------------------------------------------
extern "C" void kernel_launch(void* const* d_in, const int* in_sizes, int n_in,
                              void* d_out, int out_size, void* d_ws, size_t ws_size,
                              hipStream_t stream)
{
  const float* q_u    = (const float*)d_in[0];
  const float* q_b    = (const float*)d_in[1];
  const float* q_sig  = (const float*)d_in[2];
  const float* dtg    = (const float*)d_in[3];
  const unsigned char* wm = (const unsigned char*)d_in[4];
  const float* dproto = (const float*)d_in[5];
  const float* sproto = (const float*)d_in[6];
  const float* ema    = (const float*)d_in[7];
  const float* usage  = (const float*)d_in[8];
  float* out = (float*)d_out;

  float* wsf = (float*)d_ws;
  int*   wsi = (int*)d_ws;
  float* denom    = wsf + 16;                  // [4096]
  float* base_raw = wsf + 16 + 4096;           // [4096]
  float* wgtb     = wsf + 16 + 8192;           // [4096]
  int*   cellid   = wsi + 16 + 12288;          // [4096]
  float* mrow     = wsf + 16 + 16384;          // [4096]
  float* sum_w    = wsf + 20496;               // [16384]
  float* cnt      = wsf + 20496 + 16384;       // [16384]
  int*   tk       = wsi + 53264;               // [8]
  int*   gf       = wsi + 53272;               // [1] (+7 pad)
  int*   claimed  = wsi + 53280;               // [768]

  // PT8 (12.6 MB) + qb8 (1 MB) + quT (1 MB) park in the NDP output region,
  // which is rewritten only after the GEMM has consumed them.
  u8*    PT8 = (u8*)(out + OFF_NDP);
  u8*    qb8 = PT8 + (size_t)768 * UBD;
  float* quT = (float*)(qb8 + (size_t)NR * BD);

  prep_kernel<<<1024 + NR / 64, 256, 0, stream>>>(q_b, q_u, qb8, quT);
  transpose_mask_kernel<<<dim3(UBD / 64, 12), 256, 0, stream>>>(dproto, sproto,
                                                                usage, PT8);
  // zero raw-sum targets (MDR+MSIG) and sum_w/cnt/tk/gf/claimed (contiguous)
  hipMemsetAsync(out, 0, (size_t)OFF_MCONF * sizeof(float), stream);
  hipMemsetAsync(sum_w, 0, (2u * UBD + 16 + 768) * sizeof(float), stream);

  row_prep_kernel<<<NR, 256, 0, stream>>>(q_u, q_b, usage, ema, wm,
                                          denom, base_raw, wgtb, cellid, mrow);
  mfma_gemm_kernel<<<768, 256, 0, stream>>>(quT, qb8, PT8, out, tk, gf, claimed);
  epilogue_kernel<<<NR, 256, 0, stream>>>(q_sig, denom, base_raw, out);

  // precompute buffers consumed; zero proto accumulators and run the update path
  hipMemsetAsync(out + OFF_NDP, 0, (size_t)UBD * (RD + SD) * sizeof(float), stream);
  scatter_kernel<<<NR, 256, 0, stream>>>(dtg, q_sig, wgtb, cellid, mrow,
                                         out + OFF_NDP, out + OFF_NSP, sum_w, cnt);
  ema_proto_kernel<<<4096, 256, 0, stream>>>(dproto, sproto, sum_w, cnt,
                                             out + OFF_NDP, out + OFF_NSP);
  ema_small_kernel<<<UBD / 256, 256, 0, stream>>>(ema, usage, sum_w, cnt,
                                                  out + OFF_NEC, out + OFF_NUS);
  stats_kernel<<<1, 256, 0, stream>>>(cnt, out + OFF_NUS, out + OFF_SCAL);
}

// Round 7
// 213.972 us; speedup vs baseline: 1.9539x; 1.3005x over previous
//
#include <hip/hip_runtime.h>
#include <hip/hip_fp8.h>
#include <math.h>

#define NR 4096
#define UD 64
#define BD 256
#define SD 256
#define RD 512
#define UBD 16384
#define DECAY 0.99f

typedef unsigned char u8;
typedef __attribute__((ext_vector_type(4))) float f32x4;
typedef __attribute__((ext_vector_type(2))) long longx2;

// output offsets (in floats), concatenated in reference return order
#define OFF_MDR   0ull          // memory_delta_rule   [4096,512]
#define OFF_MSIG  2097152ull    // memory_signature    [4096,256]
#define OFF_MCONF 3145728ull    // memory_conf         [4096,1]
#define OFF_NDP   3149824ull    // new_delta_proto     [64,256,512]
#define OFF_NSP   11538432ull   // new_signature_proto [64,256,256]
#define OFF_NEC   15732736ull   // new_ema_conf        [64,256]
#define OFF_NUS   15749120ull   // new_usage           [64,256]
#define OFF_SCAL  15765504ull   // write_rate, usage_fraction, usage_entropy

static __device__ __forceinline__ u8 f2e4m3(float x) {
  __hip_fp8_e4m3 h(x);        // OCP e4m3fn, RNE+sat
  return (u8)h.__x;
}

static __device__ __forceinline__ void gll16(const void* g, void* l) {
  __builtin_amdgcn_global_load_lds(
      (const __attribute__((address_space(1))) unsigned int*)g,
      (__attribute__((address_space(3))) unsigned int*)l, 16, 0, 0);
}

// k-order permutation within a 64-block: b = ks8*32 + kg*8 + e  ->  kg*16 + ks8*8 + e
static __device__ __forceinline__ int perm64(int x) {
  return (((x >> 3) & 3) << 4) | (((x >> 5) & 1) << 3) | (x & 7);
}

// ---------------------------------------------------------------------------
// Per-row prep, 4 rows per block: denom, base_raw (usage/ema scan shared
// across the 4 rows), argmax(q_u), argmax(q_b) via wave-per-row shuffles.
__global__ __launch_bounds__(256) void row_prep_kernel(
    const float* __restrict__ q_u, const float* __restrict__ q_b,
    const float* __restrict__ usage, const float* __restrict__ ema,
    const unsigned char* __restrict__ wm,
    float* __restrict__ denom, float* __restrict__ base_raw,
    float* __restrict__ wgt, int* __restrict__ cellid, float* __restrict__ mrow)
{
  const int r0 = blockIdx.x * 4;
  const int t = threadIdx.x;
  __shared__ float s_qu[4][64];
  __shared__ float s_qbv[4][256];
  __shared__ float s_pd[4][256];
  __shared__ float s_pc[4][256];
  __shared__ int s_flag;
  {
    const int r = t >> 6, u = t & 63;
    s_qu[r][u] = q_u[(size_t)(r0 + r) * UD + u];
  }
  if (t == 0) {
    const int*   wi = (const int*)wm;
    const float* wf = (const float*)wm;
    bool is_i32 = true, is_f32 = true;
    #pragma unroll
    for (int i = 0; i < 16; ++i) {
      int v = wi[i];
      if (v != 0 && v != 1) is_i32 = false;
      float f = wf[i];
      if (f != 0.f && f != 1.f) is_f32 = false;
    }
    s_flag = is_i32 ? 2 : (is_f32 ? 1 : 0);
  }
  #pragma unroll
  for (int r = 0; r < 4; ++r)
    s_qbv[r][t] = q_b[(size_t)(r0 + r) * BD + t];
  __syncthreads();
  // shared usage/ema scan: column t, accumulate for 4 rows
  float accd[4] = {0.f, 0.f, 0.f, 0.f};
  float accc[4] = {0.f, 0.f, 0.f, 0.f};
  #pragma unroll 4
  for (int u = 0; u < UD; ++u) {
    const float us = usage[u * BD + t];
    const float em = ema[u * BD + t];
    const float vm = (us > 0.f) ? 1.f : 0.f;
    const float ev = em * vm;
    #pragma unroll
    for (int r = 0; r < 4; ++r) {
      accd[r] += s_qu[r][u] * vm;
      accc[r] += s_qu[r][u] * ev;
    }
  }
  #pragma unroll
  for (int r = 0; r < 4; ++r) {
    s_pd[r][t] = accd[r] * s_qbv[r][t];
    s_pc[r][t] = accc[r] * s_qbv[r][t];
  }
  __syncthreads();
  // wave w owns row w
  const int w = t >> 6, l = t & 63;
  float dsum = s_pd[w][l] + s_pd[w][l + 64] + s_pd[w][l + 128] + s_pd[w][l + 192];
  float csum = s_pc[w][l] + s_pc[w][l + 64] + s_pc[w][l + 128] + s_pc[w][l + 192];
  #pragma unroll
  for (int m = 1; m < 64; m <<= 1) {
    dsum += __shfl_xor(dsum, m);
    csum += __shfl_xor(csum, m);
  }
  // argmax q_b (first-index tie-break)
  float bv_ = s_qbv[w][l]; int bi_ = l;
  #pragma unroll
  for (int k = 1; k < 4; ++k) {
    const float v2 = s_qbv[w][l + k * 64];
    if (v2 > bv_) { bv_ = v2; bi_ = l + k * 64; }
  }
  #pragma unroll
  for (int m = 1; m < 64; m <<= 1) {
    const float ov = __shfl_xor(bv_, m);
    const int   oi = __shfl_xor(bi_, m);
    if (ov > bv_ || (ov == bv_ && oi < bi_)) { bv_ = ov; bi_ = oi; }
  }
  // argmax q_u
  float uv_ = s_qu[w][l & 63]; int ui_ = l;
  #pragma unroll
  for (int m = 1; m < 64; m <<= 1) {
    const float ov = __shfl_xor(uv_, m);
    const int   oi = __shfl_xor(ui_, m);
    if (ov > uv_ || (ov == uv_ && oi < ui_)) { uv_ = ov; ui_ = oi; }
  }
  if (l == 0) {
    const int n = r0 + w;
    const int fm = s_flag;
    float m;
    if (fm == 2)      m = (((const int*)wm)[n]   != 0)   ? 1.f : 0.f;
    else if (fm == 1) m = (((const float*)wm)[n] != 0.f) ? 1.f : 0.f;
    else              m = (wm[n] != 0)   ? 1.f : 0.f;
    denom[n]    = dsum;
    base_raw[n] = csum;
    wgt[n]      = uv_ * bv_ * m;
    cellid[n]   = ui_ * BD + bi_;
    mrow[n]     = m;
  }
}

// ---------------------------------------------------------------------------
// Fused prep: blocks [0,1024): q_b -> fp8 (k-permuted); blocks [1024,1088): quT
__global__ __launch_bounds__(256) void prep_kernel(
    const float* __restrict__ qb, const float* __restrict__ qu,
    u8* __restrict__ qb8, float* __restrict__ quT)
{
  if (blockIdx.x < 1024) {
    const int i = blockIdx.x * 256 + threadIdx.x;
    const int idx = i * 4;
    const int row = idx >> 8;
    const int b   = idx & 255;
    const float4 v = *(const float4*)(qb + (size_t)idx);
    u8 tmp[4] = { f2e4m3(v.x), f2e4m3(v.y), f2e4m3(v.z), f2e4m3(v.w) };
    unsigned int wv; __builtin_memcpy(&wv, tmp, 4);
    const int nb = (b & ~63) | perm64(b & 63);
    *(unsigned int*)(qb8 + (size_t)row * BD + nb) = wv;
  } else {
    __shared__ float s[64][65];
    const int n0 = (blockIdx.x - 1024) * 64;
    const int tid = threadIdx.x;
    #pragma unroll
    for (int i = 0; i < 16; ++i) {
      const int idx = tid + i * 256;
      const int r = idx >> 6, u = idx & 63;
      s[r][u] = qu[(size_t)(n0 + r) * UD + u];
    }
    __syncthreads();
    #pragma unroll
    for (int i = 0; i < 16; ++i) {
      const int idx = tid + i * 256;
      const int u = idx >> 6, r = idx & 63;
      quT[(size_t)u * NR + n0 + r] = s[r][u];
    }
  }
}

// ---------------------------------------------------------------------------
// Masked, TRANSPOSED, k-permuted fp8 proto: PT8[c][k'], c in [0,768)
__global__ __launch_bounds__(256) void transpose_mask_kernel(
    const float* __restrict__ dproto, const float* __restrict__ sproto,
    const float* __restrict__ usage, u8* __restrict__ PT8)
{
  __shared__ u8 s[64][68];
  const int k0 = blockIdx.x * 64;
  const int rblk = blockIdx.y;       // 0..11
  const float* src; int ld; int c0s;
  if (rblk < 8) { src = dproto; ld = RD; c0s = rblk * 64; }
  else          { src = sproto; ld = SD; c0s = (rblk - 8) * 64; }
  const int tid = threadIdx.x;
  const int kl = tid >> 4;
  const int rl = (tid & 15) * 4;
  #pragma unroll
  for (int i = 0; i < 4; ++i) {
    const int k = kl + i * 16;
    const bool valid = usage[k0 + k] > 0.f;
    const float4 v = *(const float4*)(src + (size_t)(k0 + k) * ld + c0s + rl);
    s[k][rl + 0] = valid ? f2e4m3(v.x) : (u8)0;
    s[k][rl + 1] = valid ? f2e4m3(v.y) : (u8)0;
    s[k][rl + 2] = valid ? f2e4m3(v.z) : (u8)0;
    s[k][rl + 3] = valid ? f2e4m3(v.w) : (u8)0;
  }
  __syncthreads();
  const int rl2 = tid >> 4;
  const int kl2 = (tid & 15) * 4;
  #pragma unroll
  for (int i = 0; i < 4; ++i) {
    const int r = rl2 + i * 16;
    u8 tmp[4] = { s[kl2 + 0][r], s[kl2 + 1][r], s[kl2 + 2][r], s[kl2 + 3][r] };
    unsigned int wv; __builtin_memcpy(&wv, tmp, 4);
    *(unsigned int*)(PT8 + (size_t)(rblk * 64 + r) * UBD + k0 + perm64(kl2)) = wv;
  }
}

// ---------------------------------------------------------------------------
// fp8 MFMA retrieve GEMM, XCC_ID work claiming, 48KB LDS -> 3 blocks/CU
// (768 blocks co-resident in one round, 96 per XCD = ticket allocation).
// sB: 64B-row double-buffered chunks; swizzle slot' = slot ^ ((row>>1)&3)
// via gll SOURCE; read granule%8 = (fr&1)*4 + (kg^((fr>>1)&3)) -> all 8
// distinct per 8-lane group (conflict-free).
__global__ __launch_bounds__(256, 3) void mfma_gemm_kernel(
    const float* __restrict__ quT, const u8* __restrict__ qb8,
    const u8* __restrict__ PT8, float* __restrict__ out,
    int* __restrict__ tk, int* __restrict__ gf, int* __restrict__ claimed)
{
  __shared__ u8 sA[2][128 * 128];   // [b-half][row][128B], staged once
  __shared__ u8 sB[2][128 * 64];    // 64-k chunk double buffer
  __shared__ int s_work;
  const int tid = threadIdx.x;

  // ---- work claim: per-XCD tickets (hardware XCC_ID), CAS-steal fallback
  if (tid == 0) {
    unsigned int xcc;
    asm volatile("s_getreg_b32 %0, hwreg(HW_REG_XCC_ID)" : "=s"(xcc));
    const int x = (int)(xcc & 7u);
    const int t = atomicAdd(&tk[x], 1);
    int w = -1;
    if (t < 96) {
      const int cand = x * 96 + t;
      if (atomicCAS(&claimed[cand], 0, 1) == 0) w = cand;
    }
    while (w < 0) {
      const int g = atomicAdd(gf, 1);
      if (g >= 768) { w = -2; break; }
      if (atomicCAS(&claimed[g], 0, 1) == 0) w = g;
    }
    s_work = w;
  }
  __syncthreads();
  const int w = s_work;
  if (w < 0) return;

  const int bx = w & 31;            // n-tile 0..31
  const int combo = w >> 5;         // 0..23 (XCD x owns combos [3x, 3x+3))
  const int by = combo >> 2;        // col-tile 0..5
  const int bz = combo & 3;         // k-split 0..3

  const int wid = tid >> 6, lane = tid & 63;
  const int n0 = bx * 128;
  const int kbeg = bz * (UBD / 4);

  float* obase; int ldO; int cc0;
  if (by < 4) { obase = out + OFF_MDR;  ldO = RD; cc0 = by * 128; }
  else        { obase = out + OFF_MSIG; ldO = SD; cc0 = (by - 4) * 128; }
  const int c0 = by * 128;          // PT8 row base

  // ---- A staging lane geometry (8 rows x 8 slots of 16B per 1KB gll call)
  const int lrowA = lane >> 3;
  const int csrcA = ((lane & 7) ^ lrowA) * 16;
  const u8* gA = qb8 + (size_t)(n0 + lrowA) * BD + csrcA;
  // ---- B staging lane geometry (16 rows x 4 slots of 16B per 1KB gll call)
  const int lrowB = lane >> 2;
  const int srcslotB = (lane & 3) ^ ((lrowB >> 1) & 3);
  const u8* gB = PT8 + (size_t)(c0 + wid * 16 + lrowB) * UBD + kbeg + srcslotB * 16;

  // ---- fragment geometry
  const int wr = (wid >> 1) * 64, wc = (wid & 1) * 64;
  const int fr = lane & 15;
  const int kg = lane >> 4;
  int aoff[4], boff[4];
  #pragma unroll
  for (int m = 0; m < 4; ++m) aoff[m] = (wr + m * 16 + fr) * 128;
  #pragma unroll
  for (int nn = 0; nn < 4; ++nn) boff[nn] = (wc + nn * 16 + fr) * 64;
  int slothA[2];
  #pragma unroll
  for (int bq = 0; bq < 2; ++bq) slothA[bq] = ((bq * 4 + kg) ^ (fr & 7)) * 16;
  const int slotB16 = (kg ^ ((fr >> 1) & 3)) * 16;

  f32x4 accm[4][4];
  #pragma unroll
  for (int m = 0; m < 4; ++m)
    #pragma unroll
    for (int nn = 0; nn < 4; ++nn)
      accm[m][nn] = (f32x4){0.f, 0.f, 0.f, 0.f};

  // ---- prologue: both A halves + B chunk 0
  #pragma unroll
  for (int i = 0; i < 4; ++i) {
    const int ro = wid * 32 + i * 8;
    gll16(gA + (size_t)ro * BD,       &sA[0][ro * 128]);
    gll16(gA + (size_t)ro * BD + 128, &sA[1][ro * 128]);
  }
  #pragma unroll
  for (int i = 0; i < 2; ++i)
    gll16(gB + (size_t)(i * 64) * UBD, &sB[0][(i * 64 + wid * 16) * 64]);
  __syncthreads();

  const float* quTb = quT + n0 + wr + kg * 4;
  const int ubase = kbeg >> 8;
  f32x4 accu[4][4];

  for (int ph = 0; ph < 64; ++ph) {
    const int buf  = ph & 1;
    const int half = (ph >> 1) & 1;
    const int bq   = ph & 1;
    // issue next chunk into the other buffer (drained by the barrier)
    if (ph < 63) {
      const u8* gs = gB + (size_t)(ph + 1) * 64;
      #pragma unroll
      for (int i = 0; i < 2; ++i)
        gll16(gs + (size_t)(i * 64) * UBD, &sB[buf ^ 1][(i * 64 + wid * 16) * 64]);
    }
    const u8* sa = sA[half];
    const u8* sb = sB[buf];
    longx2 av[4], bv[4];
    #pragma unroll
    for (int m = 0; m < 4; ++m)
      av[m] = *(const longx2*)(sa + aoff[m] + slothA[bq]);
    #pragma unroll
    for (int nn = 0; nn < 4; ++nn)
      bv[nn] = *(const longx2*)(sb + boff[nn] + slotB16);
    const bool first = (ph & 3) == 0;
    #pragma unroll
    for (int m = 0; m < 4; ++m)
      #pragma unroll
      for (int nn = 0; nn < 4; ++nn) {
        if (first)
          accu[m][nn] = __builtin_amdgcn_mfma_f32_16x16x32_fp8_fp8(
              av[m].x, bv[nn].x, (f32x4){0.f, 0.f, 0.f, 0.f}, 0, 0, 0);
        else
          accu[m][nn] = __builtin_amdgcn_mfma_f32_16x16x32_fp8_fp8(
              av[m].x, bv[nn].x, accu[m][nn], 0, 0, 0);
        accu[m][nn] = __builtin_amdgcn_mfma_f32_16x16x32_fp8_fp8(
            av[m].y, bv[nn].y, accu[m][nn], 0, 0, 0);
      }
    __syncthreads();
    if ((ph & 3) == 3) {
      // fold exact f32 q_u for the completed u-chunk
      const float* qp = quTb + (size_t)(ubase + (ph >> 2)) * NR;
      #pragma unroll
      for (int m = 0; m < 4; ++m) {
        const f32x4 qv = *(const f32x4*)(qp + m * 16);
        #pragma unroll
        for (int nn = 0; nn < 4; ++nn)
          accm[m][nn] += qv * accu[m][nn];
      }
    }
  }

  // ---- epilogue: atomic accumulate raw sums (scaled later by 1/denom)
  #pragma unroll
  for (int m = 0; m < 4; ++m) {
    #pragma unroll
    for (int nn = 0; nn < 4; ++nn) {
      const int c = cc0 + wc + nn * 16 + fr;
      #pragma unroll
      for (int j = 0; j < 4; ++j) {
        const int r = n0 + wr + m * 16 + kg * 4 + j;
        atomicAdd(obase + (size_t)r * ldO + c, accm[m][nn][j]);
      }
    }
  }
}

// ---------------------------------------------------------------------------
// Scale raw GEMM sums by 1/denom in place; fuse memory_conf (cosine)
__global__ __launch_bounds__(256) void epilogue_kernel(
    const float* __restrict__ q_sigma, const float* __restrict__ denom,
    const float* __restrict__ base_raw, float* __restrict__ out)
{
  const int n = blockIdx.x;
  const int t = threadIdx.x;
  __shared__ float r1[256], r2[256], r3[256];
  const float d = denom[n];
  const float scale = (d > 0.f) ? (1.f / fmaxf(d, 1e-6f)) : 0.f;
  float* mdr = out + OFF_MDR + (size_t)n * RD;
  mdr[t]       *= scale;
  mdr[t + 256] *= scale;
  float* msig = out + OFF_MSIG + (size_t)n * SD;
  const float s = msig[t] * scale;
  msig[t] = s;
  const float a = q_sigma[(size_t)n * SD + t];
  const float b = s + 1e-6f;
  r1[t] = a * a; r2[t] = b * b; r3[t] = a * b;
  __syncthreads();
  for (int st = 128; st > 0; st >>= 1) {
    if (t < st) { r1[t] += r1[t + st]; r2[t] += r2[t + st]; r3[t] += r3[t + st]; }
    __syncthreads();
  }
  if (t == 0) {
    const float na = fmaxf(sqrtf(r1[0]), 1e-12f);
    const float nb = fmaxf(sqrtf(r2[0]), 1e-12f);
    const float cosv = r3[0] / (na * nb);
    const float agree = 0.5f * (1.f + cosv);
    const float base = (d > 0.f) ? base_raw[n] / fmaxf(d, 1e-6f) : 0.f;
    out[OFF_MCONF + n] = fminf(fmaxf(base * agree, 0.f), 1.f);
  }
}

// ---------------------------------------------------------------------------
// Per-row sum_w/cnt accumulation (replaces the per-element sums pass)
__global__ __launch_bounds__(256) void small_sums_kernel(
    const float* __restrict__ wgt, const int* __restrict__ cellid,
    const float* __restrict__ mrow,
    float* __restrict__ sum_w, float* __restrict__ cnt)
{
  const int n = blockIdx.x * 256 + threadIdx.x;
  if (n < NR && mrow[n] != 0.f) {
    atomicAdd(&sum_w[cellid[n]], wgt[n]);
    atomicAdd(&cnt[cellid[n]], 1.f);
  }
}

// ---------------------------------------------------------------------------
// out = cnt>0 ? DECAY*proto : proto   (scatter2 then adds the mean terms)
__global__ __launch_bounds__(256) void ema_copy_kernel(
    const float* __restrict__ dproto, const float* __restrict__ sproto,
    const float* __restrict__ cnt,
    float* __restrict__ outd, float* __restrict__ outs)
{
  const size_t nd = (size_t)UBD * RD;          // 8388608
  const size_t total = nd + (size_t)UBD * SD;  // 12582912
  for (size_t i = (size_t)blockIdx.x * 256 + threadIdx.x; i < total;
       i += (size_t)gridDim.x * 256) {
    if (i < nd) {
      const float p = dproto[i];
      outd[i] = (cnt[(int)(i >> 9)] > 0.f) ? DECAY * p : p;
    } else {
      const size_t j = i - nd;
      const float p = sproto[j];
      outs[j] = (cnt[(int)(j >> 8)] > 0.f) ? DECAY * p : p;
    }
  }
}

// ---------------------------------------------------------------------------
// Add (1-DECAY) * (w/cs) * target onto the DECAY-scaled protos
__global__ __launch_bounds__(256) void scatter2_kernel(
    const float* __restrict__ dtarget, const float* __restrict__ q_sigma,
    const float* __restrict__ wgt, const int* __restrict__ cellid,
    const float* __restrict__ mrow, const float* __restrict__ sum_w,
    float* __restrict__ outd, float* __restrict__ outs)
{
  const int n = blockIdx.x;
  if (mrow[n] == 0.f) return;
  const int t = threadIdx.x;
  const int c = cellid[n];
  const float cs = fmaxf(sum_w[c], 1e-6f);
  const float coef = (1.0f - DECAY) * wgt[n] / cs;
  atomicAdd(&outd[(size_t)c * RD + t],       dtarget[(size_t)n * RD + t] * coef);
  atomicAdd(&outd[(size_t)c * RD + t + 256], dtarget[(size_t)n * RD + t + 256] * coef);
  atomicAdd(&outs[(size_t)c * SD + t],       q_sigma[(size_t)n * SD + t] * coef);
}

// ---------------------------------------------------------------------------
__global__ __launch_bounds__(256) void ema_small_kernel(
    const float* __restrict__ ema, const float* __restrict__ usage,
    const float* __restrict__ sum_w, const float* __restrict__ cnt,
    float* __restrict__ out_ec, float* __restrict__ out_us)
{
  const int i = blockIdx.x * 256 + threadIdx.x;
  if (i < UBD) {
    const float c = cnt[i];
    const float cm = sum_w[i] / fmaxf(c, 1.f);
    out_ec[i] = (c > 0.f) ? DECAY * ema[i] + (1.f - DECAY) * cm : ema[i];
    out_us[i] = usage[i] + c;
  }
}

// ---------------------------------------------------------------------------
// write_rate, usage_fraction, usage_entropy (single block)
__global__ __launch_bounds__(256) void stats_kernel(
    const float* __restrict__ cnt, const float* __restrict__ new_us,
    float* __restrict__ out_scalars)
{
  const int t = threadIdx.x;
  __shared__ float r1[256], r2[256], r3[256];
  float scnt = 0.f, snz = 0.f, sus = 0.f;
  for (int i = t; i < UBD; i += 256) {
    const float c = cnt[i]; scnt += c;
    const float u = new_us[i];
    if (u > 0.f) snz += 1.f;
    sus += u;
  }
  r1[t] = scnt; r2[t] = snz; r3[t] = sus;
  __syncthreads();
  for (int s = 128; s > 0; s >>= 1) {
    if (t < s) { r1[t] += r1[t + s]; r2[t] += r2[t + s]; r3[t] += r3[t + s]; }
    __syncthreads();
  }
  const float total_cnt = r1[0], total_nz = r2[0], total_us = r3[0];
  __syncthreads();
  const float S = fmaxf(total_us, 1e-6f);
  float ent = 0.f;
  for (int i = t; i < UBD; i += 256) {
    const float d = new_us[i] / S;
    ent += d * logf(d + 1e-6f);
  }
  r1[t] = ent;
  __syncthreads();
  for (int s = 128; s > 0; s >>= 1) {
    if (t < s) { r1[t] += r1[t + s]; }
    __syncthreads();
  }
  if (t == 0) {
    out_scalars[0] = total_cnt / (float)NR;
    out_scalars[1] = total_nz / (float)UBD;
    out_scalars[2] = -r1[0] / 9.70406053f;   // ln(16384)
  }
}

// ---------------------------------------------------------------------------
extern "C" void kernel_launch(void* const* d_in, const int* in_sizes, int n_in,
                              void* d_out, int out_size, void* d_ws, size_t ws_size,
                              hipStream_t stream)
{
  const float* q_u    = (const float*)d_in[0];
  const float* q_b    = (const float*)d_in[1];
  const float* q_sig  = (const float*)d_in[2];
  const float* dtg    = (const float*)d_in[3];
  const unsigned char* wm = (const unsigned char*)d_in[4];
  const float* dproto = (const float*)d_in[5];
  const float* sproto = (const float*)d_in[6];
  const float* ema    = (const float*)d_in[7];
  const float* usage  = (const float*)d_in[8];
  float* out = (float*)d_out;

  float* wsf = (float*)d_ws;
  int*   wsi = (int*)d_ws;
  float* denom    = wsf + 16;                  // [4096]
  float* base_raw = wsf + 16 + 4096;           // [4096]
  float* wgtb     = wsf + 16 + 8192;           // [4096]
  int*   cellid   = wsi + 16 + 12288;          // [4096]
  float* mrow     = wsf + 16 + 16384;          // [4096]
  float* sum_w    = wsf + 20496;               // [16384]
  float* cnt      = wsf + 20496 + 16384;       // [16384]
  int*   tk       = wsi + 53264;               // [8]
  int*   gf       = wsi + 53272;               // [1] (+7 pad)
  int*   claimed  = wsi + 53280;               // [768]

  // PT8 (12.6 MB) + qb8 (1 MB) + quT (1 MB) park in the NDP output region,
  // which is rewritten (by ema_copy/scatter2) only after the GEMM.
  u8*    PT8 = (u8*)(out + OFF_NDP);
  u8*    qb8 = PT8 + (size_t)768 * UBD;
  float* quT = (float*)(qb8 + (size_t)NR * BD);

  prep_kernel<<<1024 + NR / 64, 256, 0, stream>>>(q_b, q_u, qb8, quT);
  transpose_mask_kernel<<<dim3(UBD / 64, 12), 256, 0, stream>>>(dproto, sproto,
                                                                usage, PT8);
  // zero raw-sum targets (MDR+MSIG) and sum_w/cnt/tk/gf/claimed (contiguous)
  hipMemsetAsync(out, 0, (size_t)OFF_MCONF * sizeof(float), stream);
  hipMemsetAsync(sum_w, 0, (2u * UBD + 16 + 768) * sizeof(float), stream);

  row_prep_kernel<<<NR / 4, 256, 0, stream>>>(q_u, q_b, usage, ema, wm,
                                              denom, base_raw, wgtb, cellid, mrow);
  small_sums_kernel<<<NR / 256, 256, 0, stream>>>(wgtb, cellid, mrow, sum_w, cnt);
  mfma_gemm_kernel<<<768, 256, 0, stream>>>(quT, qb8, PT8, out, tk, gf, claimed);
  epilogue_kernel<<<NR, 256, 0, stream>>>(q_sig, denom, base_raw, out);

  // precompute buffers consumed; write EMA base then scatter the mean terms
  ema_copy_kernel<<<4096, 256, 0, stream>>>(dproto, sproto, cnt,
                                            out + OFF_NDP, out + OFF_NSP);
  scatter2_kernel<<<NR, 256, 0, stream>>>(dtg, q_sig, wgtb, cellid, mrow, sum_w,
                                          out + OFF_NDP, out + OFF_NSP);
  ema_small_kernel<<<UBD / 256, 256, 0, stream>>>(ema, usage, sum_w, cnt,
                                                  out + OFF_NEC, out + OFF_NUS);
  stats_kernel<<<1, 256, 0, stream>>>(cnt, out + OFF_NUS, out + OFF_SCAL);
}